// Round 1
// baseline (434.262 us; speedup 1.0000x reference)
//
#include <hip/hip_runtime.h>

#define NB 32
#define NN 64
#define ND 256
constexpr float PEN = 10000.0f;
constexpr float TEMP_ = 0.05f;

__device__ __forceinline__ float clip50(float x) { return fminf(fmaxf(x, -50.0f), 50.0f); }

// ---------------- K1: U = clip(s_t)@W1a + b1 ; V = clip(s_t1)@W1b ----------------
__global__ __launch_bounds__(256)
void k1_uv(const float* __restrict__ s_t, const float* __restrict__ s_t1,
           const float* __restrict__ W1, const float* __restrict__ b1,
           float* __restrict__ U, float* __restrict__ V)
{
    const int half = blockIdx.x >> 8;      // 0 -> U, 1 -> V
    const int rb   = blockIdx.x & 255;     // 8 rows per block
    const int tid  = threadIdx.x;
    const float* src = half ? s_t1 : s_t;
    const float* W   = W1 + half * ND * ND;
    float* dst = half ? V : U;
    __shared__ float sL[8 * ND];
    const int rbase = rb * 8;
    for (int idx = tid; idx < 8 * ND; idx += 256)
        sL[idx] = clip50(src[rbase * ND + idx]);
    __syncthreads();
    const int c = tid;
    float acc[8] = {0.f,0.f,0.f,0.f,0.f,0.f,0.f,0.f};
    for (int k = 0; k < ND; ++k) {
        const float w = W[k * ND + c];
        #pragma unroll
        for (int r = 0; r < 8; ++r) acc[r] = fmaf(sL[r * ND + k], w, acc[r]);
    }
    const float bias = half ? 0.0f : b1[c];
    #pragma unroll
    for (int r = 0; r < 8; ++r) dst[(rbase + r) * ND + c] = acc[r] + bias;
}

// ---------------- K2: per-(b,i) pair-MLP -> initial log_alpha row ----------------
// LDS dbuf (64 KB) lifecycle: |diff| matrix (swizzled) -> h1 (swizzled) -> layer2 partials.
// Swizzle: element (row j, col k) lives at j*256 + (k ^ (4*(j>>3))).
__global__ __launch_bounds__(256)
void k2_scores(const float* __restrict__ s_t, const float* __restrict__ s_t1,
               const float* __restrict__ W1, const float* __restrict__ W2,
               const float* __restrict__ b2, const float* __restrict__ W3,
               const float* __restrict__ b3, const float* __restrict__ alive_t,
               const float* __restrict__ alive_t1,
               const float* __restrict__ U, const float* __restrict__ V,
               float* __restrict__ laG)
{
    __shared__ float dbuf[NN * ND];
    const int tid = threadIdx.x;
    const int bi  = blockIdx.x;            // b*64 + i
    const int b   = bi >> 6;

    // phase 1: fill |diff|. thread tid owns column k = tid for all j.
    const float stiv = clip50(s_t[bi * ND + tid]);
    const float* s1b = s_t1 + b * NN * ND;
    for (int j = 0; j < NN; ++j) {
        const float v = fabsf(stiv - clip50(s1b[j * ND + tid]));
        dbuf[j * ND + (tid ^ ((j >> 3) << 2))] = v;
    }
    __syncthreads();

    // phase 2: layer 1 pairwise part: acc[r][q] = sum_k d[j0+r][k] * W1c[k][c0+q]
    const int tj = tid >> 5;               // 0..7
    const int tc = tid & 31;               // 0..31
    const int j0 = tj * 8, c0 = tc * 8;
    const int fx = tj << 2;                // (j0+r)>>3 == tj for r<8
    const float* W1c = W1 + 2 * ND * ND;
    float acc[8][8];
    #pragma unroll
    for (int r = 0; r < 8; ++r)
        #pragma unroll
        for (int q = 0; q < 8; ++q) acc[r][q] = 0.f;

    #pragma unroll 2
    for (int k = 0; k < ND; ++k) {
        const float4 wa = *(const float4*)(W1c + k * ND + c0);
        const float4 wb = *(const float4*)(W1c + k * ND + c0 + 4);
        const int ks = k ^ fx;
        float dv[8];
        #pragma unroll
        for (int r = 0; r < 8; ++r) dv[r] = dbuf[(j0 + r) * ND + ks];
        #pragma unroll
        for (int r = 0; r < 8; ++r) {
            acc[r][0] = fmaf(dv[r], wa.x, acc[r][0]);
            acc[r][1] = fmaf(dv[r], wa.y, acc[r][1]);
            acc[r][2] = fmaf(dv[r], wa.z, acc[r][2]);
            acc[r][3] = fmaf(dv[r], wa.w, acc[r][3]);
            acc[r][4] = fmaf(dv[r], wb.x, acc[r][4]);
            acc[r][5] = fmaf(dv[r], wb.y, acc[r][5]);
            acc[r][6] = fmaf(dv[r], wb.z, acc[r][6]);
            acc[r][7] = fmaf(dv[r], wb.w, acc[r][7]);
        }
    }
    __syncthreads();  // all |diff| reads complete before overwriting with h1

    // h1 = relu(acc + U[b,i] + V[b,j]) -> dbuf (same swizzle)
    {
        const float* Urow = U + bi * ND;
        const float4 ua = *(const float4*)(Urow + c0);
        const float4 ub = *(const float4*)(Urow + c0 + 4);
        #pragma unroll
        for (int r = 0; r < 8; ++r) {
            const float* Vrow = V + (b * NN + j0 + r) * ND;
            const float4 va = *(const float4*)(Vrow + c0);
            const float4 vb = *(const float4*)(Vrow + c0 + 4);
            float4 ha, hb;
            ha.x = fmaxf(acc[r][0] + ua.x + va.x, 0.f);
            ha.y = fmaxf(acc[r][1] + ua.y + va.y, 0.f);
            ha.z = fmaxf(acc[r][2] + ua.z + va.z, 0.f);
            ha.w = fmaxf(acc[r][3] + ua.w + va.w, 0.f);
            hb.x = fmaxf(acc[r][4] + ub.x + vb.x, 0.f);
            hb.y = fmaxf(acc[r][5] + ub.y + vb.y, 0.f);
            hb.z = fmaxf(acc[r][6] + ub.z + vb.z, 0.f);
            hb.w = fmaxf(acc[r][7] + ub.w + vb.w, 0.f);
            *(float4*)(dbuf + (j0 + r) * ND + ((c0    ) ^ fx)) = ha;
            *(float4*)(dbuf + (j0 + r) * ND + ((c0 + 4) ^ fx)) = hb;
        }
    }
    __syncthreads();

    // phase 3: layer 2. wave w covers c in [64w, 64w+64); 8x8 (j,m) tile per lane.
    const int w    = tid >> 6;
    const int lane = tid & 63;
    const int tj2  = lane >> 3;            // 0..7
    const int tm   = lane & 7;             // 0..7
    const int j0b = tj2 * 8, m0 = tm * 8;
    const int fx2 = tj2 << 2;
    float acc2[8][8];
    #pragma unroll
    for (int r = 0; r < 8; ++r)
        #pragma unroll
        for (int q = 0; q < 8; ++q) acc2[r][q] = 0.f;

    #pragma unroll 2
    for (int cc = 0; cc < 64; ++cc) {
        const int c = (w << 6) + cc;
        const float4 w2a = *(const float4*)(W2 + c * 64 + m0);
        const float4 w2b = *(const float4*)(W2 + c * 64 + m0 + 4);
        const int cs = c ^ fx2;
        float hv[8];
        #pragma unroll
        for (int r = 0; r < 8; ++r) hv[r] = dbuf[(j0b + r) * ND + cs];
        #pragma unroll
        for (int r = 0; r < 8; ++r) {
            acc2[r][0] = fmaf(hv[r], w2a.x, acc2[r][0]);
            acc2[r][1] = fmaf(hv[r], w2a.y, acc2[r][1]);
            acc2[r][2] = fmaf(hv[r], w2a.z, acc2[r][2]);
            acc2[r][3] = fmaf(hv[r], w2a.w, acc2[r][3]);
            acc2[r][4] = fmaf(hv[r], w2b.x, acc2[r][4]);
            acc2[r][5] = fmaf(hv[r], w2b.y, acc2[r][5]);
            acc2[r][6] = fmaf(hv[r], w2b.z, acc2[r][6]);
            acc2[r][7] = fmaf(hv[r], w2b.w, acc2[r][7]);
        }
    }
    __syncthreads();  // all h1 reads done before overwriting with partials

    #pragma unroll
    for (int r = 0; r < 8; ++r) {
        const float4 pa = make_float4(acc2[r][0], acc2[r][1], acc2[r][2], acc2[r][3]);
        const float4 pb = make_float4(acc2[r][4], acc2[r][5], acc2[r][6], acc2[r][7]);
        *(float4*)(dbuf + (w << 12) + (j0b + r) * 64 + m0)     = pa;
        *(float4*)(dbuf + (w << 12) + (j0b + r) * 64 + m0 + 4) = pb;
    }
    __syncthreads();

    // final: h2 = relu(sum_w partials + b2); score = h2@W3 + b3; penalties; la0
    const int m = lane;
    const float w3v = W3[m];
    const float b2v = b2[m];
    const float b3v = b3[0];
    const float pen_i = (alive_t[bi] < 0.5f) ? PEN : 0.0f;
    #pragma unroll
    for (int t = 0; t < 16; ++t) {
        const int j = (t << 2) + w;
        const int idx = (j << 6) + m;      // == t*256 + tid
        const float s = dbuf[idx] + dbuf[4096 + idx] + dbuf[8192 + idx] + dbuf[12288 + idx];
        float val = fmaxf(s + b2v, 0.0f) * w3v;
        #pragma unroll
        for (int off = 1; off < 64; off <<= 1)
            val += __shfl_xor(val, off, 64);
        if (lane == 0) {
            const float sc = val + b3v;
            const float pj = (alive_t1[b * NN + j] < 0.5f) ? PEN : 0.0f;
            const float sp = sc - pen_i - pj;
            const float la = fminf(fmaxf(sp, -PEN), PEN) / TEMP_;   // = -clip(-sp)/TEMP
            laG[bi * NN + j] = la;
        }
    }
}

// ---------------- K3: Sinkhorn (20 iters) + argmax/matched ----------------
__global__ __launch_bounds__(256)
void k3_sinkhorn(const float* __restrict__ laG, const float* __restrict__ alive_t,
                 const float* __restrict__ alive_t1, float* __restrict__ out)
{
    __shared__ float la[NN * 65];          // pad 65: both passes conflict-free
    const int b = blockIdx.x, tid = threadIdx.x;
    for (int idx = tid; idx < NN * NN; idx += 256)
        la[(idx >> 6) * 65 + (idx & 63)] = laG[b * NN * NN + idx];
    __syncthreads();

    const int g = tid >> 2;                // row/col index 0..63
    const int q = tid & 3;                 // quarter
    for (int it = 0; it < 20; ++it) {
        {   // axis=2: normalize rows (over c)
            float m = -INFINITY;
            #pragma unroll
            for (int t = 0; t < 16; ++t) m = fmaxf(m, la[g * 65 + q * 16 + t]);
            m = fmaxf(m, __shfl_xor(m, 1, 64));
            m = fmaxf(m, __shfl_xor(m, 2, 64));
            float s = 0.f;
            #pragma unroll
            for (int t = 0; t < 16; ++t) s += expf(la[g * 65 + q * 16 + t] - m);
            s += __shfl_xor(s, 1, 64);
            s += __shfl_xor(s, 2, 64);
            const float lse = m + logf(s);
            #pragma unroll
            for (int t = 0; t < 16; ++t) la[g * 65 + q * 16 + t] -= lse;
        }
        __syncthreads();
        {   // axis=1: normalize cols (over r)
            float m = -INFINITY;
            #pragma unroll
            for (int t = 0; t < 16; ++t) m = fmaxf(m, la[(q * 16 + t) * 65 + g]);
            m = fmaxf(m, __shfl_xor(m, 1, 64));
            m = fmaxf(m, __shfl_xor(m, 2, 64));
            float s = 0.f;
            #pragma unroll
            for (int t = 0; t < 16; ++t) s += expf(la[(q * 16 + t) * 65 + g] - m);
            s += __shfl_xor(s, 1, 64);
            s += __shfl_xor(s, 2, 64);
            const float lse = m + logf(s);
            #pragma unroll
            for (int t = 0; t < 16; ++t) la[(q * 16 + t) * 65 + g] -= lse;
        }
        __syncthreads();
    }

    // argmax over axis 2 with first-index tie-break; outputs
    float bm = -INFINITY; int bidx = 0;
    #pragma unroll
    for (int t = 0; t < 16; ++t) {
        const float v = la[g * 65 + q * 16 + t];
        if (v > bm) { bm = v; bidx = q * 16 + t; }
    }
    #pragma unroll
    for (int off = 1; off < 4; off <<= 1) {
        const float om = __shfl_xor(bm, off, 64);
        const int   oi = __shfl_xor(bidx, off, 64);
        if (om > bm || (om == bm && oi < bidx)) { bm = om; bidx = oi; }
    }
    if (q == 0) {
        const float conf = expf(bm);
        const float at  = alive_t[b * NN + g];
        const float at1 = alive_t1[b * NN + bidx];
        const float matched = (at > 0.5f && at1 > 0.5f && conf > 0.3f) ? 1.0f : 0.0f;
        out[b * NN + g] = (float)bidx;                 // perm (written as float)
        out[NB * NN + b * NN + g] = matched;           // matched
    }
}

extern "C" void kernel_launch(void* const* d_in, const int* in_sizes, int n_in,
                              void* d_out, int out_size, void* d_ws, size_t ws_size,
                              hipStream_t stream)
{
    (void)in_sizes; (void)n_in; (void)out_size; (void)ws_size;
    const float* s_t      = (const float*)d_in[0];
    const float* s_t1     = (const float*)d_in[1];
    const float* alive_t  = (const float*)d_in[2];
    const float* alive_t1 = (const float*)d_in[3];
    const float* W1 = (const float*)d_in[4];
    const float* b1 = (const float*)d_in[5];
    const float* W2 = (const float*)d_in[6];
    const float* b2 = (const float*)d_in[7];
    const float* W3 = (const float*)d_in[8];
    const float* b3 = (const float*)d_in[9];

    float* U   = (float*)d_ws;                 // 2048*256
    float* V   = U + NB * NN * ND;             // 2048*256
    float* laG = V + NB * NN * ND;             // 32*64*64
    float* out = (float*)d_out;

    hipLaunchKernelGGL(k1_uv, dim3(512), dim3(256), 0, stream, s_t, s_t1, W1, b1, U, V);
    hipLaunchKernelGGL(k2_scores, dim3(NB * NN), dim3(256), 0, stream,
                       s_t, s_t1, W1, W2, b2, W3, b3, alive_t, alive_t1, U, V, laG);
    hipLaunchKernelGGL(k3_sinkhorn, dim3(NB), dim3(256), 0, stream,
                       laG, alive_t, alive_t1, out);
}

// Round 2
// 407.168 us; speedup vs baseline: 1.0665x; 1.0665x over previous
//
#include <hip/hip_runtime.h>

#define NB 32
#define NN 64
#define ND 256
constexpr float PEN = 10000.0f;
constexpr float TEMP_ = 0.05f;

__device__ __forceinline__ float clip50(float x) { return fminf(fmaxf(x, -50.0f), 50.0f); }

// ---------------- K1: U = clip(s_t)@W1a + b1 ; V = clip(s_t1)@W1b ----------------
// 256 blocks: half = blockIdx>>7 (0->U, 1->V), 16 rows per block.
__global__ __launch_bounds__(256)
void k1_uv(const float* __restrict__ s_t, const float* __restrict__ s_t1,
           const float* __restrict__ W1, const float* __restrict__ b1,
           float* __restrict__ U, float* __restrict__ V)
{
    const int half = blockIdx.x >> 7;
    const int rb   = blockIdx.x & 127;
    const int tid  = threadIdx.x;
    const float* src = half ? s_t1 : s_t;
    const float* W   = W1 + half * ND * ND;
    float* dst = half ? V : U;
    __shared__ float sL[16 * ND];
    const int rbase = rb * 16;
    #pragma unroll
    for (int t = 0; t < 4; ++t) {
        const int i4 = ((t << 8) + tid) << 2;          // float offset, 16B aligned
        float4 a = *(const float4*)(src + rbase * ND + i4);
        a.x = clip50(a.x); a.y = clip50(a.y); a.z = clip50(a.z); a.w = clip50(a.w);
        *(float4*)(sL + i4) = a;
    }
    __syncthreads();
    const int c0 = (tid & 63) << 2;                    // 4 cols
    const int r0 = (tid >> 6) << 2;                    // 4 rows (same for whole wave)
    float acc[4][4];
    #pragma unroll
    for (int r = 0; r < 4; ++r)
        #pragma unroll
        for (int q = 0; q < 4; ++q) acc[r][q] = 0.f;

    for (int k4 = 0; k4 < ND; k4 += 4) {
        float4 sv[4];
        #pragma unroll
        for (int r = 0; r < 4; ++r) sv[r] = *(const float4*)(sL + (r0 + r) * ND + k4); // broadcast
        #pragma unroll
        for (int kk = 0; kk < 4; ++kk) {
            const float4 wv = *(const float4*)(W + (k4 + kk) * ND + c0);
            #pragma unroll
            for (int r = 0; r < 4; ++r) {
                const float s = (&sv[r].x)[kk];
                acc[r][0] = fmaf(s, wv.x, acc[r][0]);
                acc[r][1] = fmaf(s, wv.y, acc[r][1]);
                acc[r][2] = fmaf(s, wv.z, acc[r][2]);
                acc[r][3] = fmaf(s, wv.w, acc[r][3]);
            }
        }
    }
    float4 bias = make_float4(0.f, 0.f, 0.f, 0.f);
    if (!half) bias = *(const float4*)(b1 + c0);
    #pragma unroll
    for (int r = 0; r < 4; ++r) {
        float4 o;
        o.x = acc[r][0] + bias.x; o.y = acc[r][1] + bias.y;
        o.z = acc[r][2] + bias.z; o.w = acc[r][3] + bias.w;
        *(float4*)(dst + (rbase + r0 + r) * ND + c0) = o;
    }
}

// ---------------- K2: per-(b,i) pair-MLP -> initial log_alpha row ----------------
// LDS dbuf (64 KB) lifecycle: |diff| (swizzled) -> h1 (swizzled) -> layer2 partials.
// Swizzle: element (row j, col k) at j*256 + (k ^ (4*(j>>3))). XOR is a multiple
// of 4, so aligned float4 chunks stay contiguous; at b128 granularity the 8 rows
// of a lane's tile read 8 distinct bank-quads -> conflict-free.
__global__ __launch_bounds__(256)
void k2_scores(const float* __restrict__ s_t, const float* __restrict__ s_t1,
               const float* __restrict__ W1, const float* __restrict__ W2,
               const float* __restrict__ b2, const float* __restrict__ W3,
               const float* __restrict__ b3, const float* __restrict__ alive_t,
               const float* __restrict__ alive_t1,
               const float* __restrict__ U, const float* __restrict__ V,
               float* __restrict__ laG)
{
    __shared__ float dbuf[NN * ND];
    const int tid = threadIdx.x;
    const int bi  = blockIdx.x;            // b*64 + i
    const int b   = bi >> 6;

    // phase 1: fill |diff| with float4 loads + b128 LDS writes.
    {
        const float* stb = s_t + bi * ND;
        const float* s1b = s_t1 + b * NN * ND;
        #pragma unroll
        for (int t = 0; t < 16; ++t) {
            const int idx = (t << 8) + tid;        // float4 slot 0..4095
            const int j   = idx >> 6;
            const int c4  = (idx & 63) << 2;
            const float4 a  = *(const float4*)(stb + c4);
            const float4 v1 = *(const float4*)(s1b + j * ND + c4);
            float4 d;
            d.x = fabsf(clip50(a.x) - clip50(v1.x));
            d.y = fabsf(clip50(a.y) - clip50(v1.y));
            d.z = fabsf(clip50(a.z) - clip50(v1.z));
            d.w = fabsf(clip50(a.w) - clip50(v1.w));
            *(float4*)(dbuf + j * ND + (c4 ^ ((j >> 3) << 2))) = d;
        }
    }
    __syncthreads();

    // phase 2: layer 1 pairwise part: acc[r][q] = sum_k d[j0+r][k] * W1c[k][c0+q]
    const int tj = tid >> 5;               // 0..7
    const int tc = tid & 31;               // 0..31
    const int j0 = tj * 8, c0 = tc * 8;
    const int fx = tj << 2;
    const float* W1c = W1 + 2 * ND * ND;
    float acc[8][8];
    #pragma unroll
    for (int r = 0; r < 8; ++r)
        #pragma unroll
        for (int q = 0; q < 8; ++q) acc[r][q] = 0.f;

    for (int k4 = 0; k4 < ND; k4 += 4) {
        const int ks = k4 ^ fx;
        float4 dv[8];
        #pragma unroll
        for (int r = 0; r < 8; ++r) dv[r] = *(const float4*)(dbuf + (j0 + r) * ND + ks);
        #pragma unroll
        for (int kk = 0; kk < 4; ++kk) {
            const float4 wa = *(const float4*)(W1c + (k4 + kk) * ND + c0);
            const float4 wb = *(const float4*)(W1c + (k4 + kk) * ND + c0 + 4);
            #pragma unroll
            for (int r = 0; r < 8; ++r) {
                const float d = (&dv[r].x)[kk];
                acc[r][0] = fmaf(d, wa.x, acc[r][0]);
                acc[r][1] = fmaf(d, wa.y, acc[r][1]);
                acc[r][2] = fmaf(d, wa.z, acc[r][2]);
                acc[r][3] = fmaf(d, wa.w, acc[r][3]);
                acc[r][4] = fmaf(d, wb.x, acc[r][4]);
                acc[r][5] = fmaf(d, wb.y, acc[r][5]);
                acc[r][6] = fmaf(d, wb.z, acc[r][6]);
                acc[r][7] = fmaf(d, wb.w, acc[r][7]);
            }
        }
    }
    __syncthreads();  // all |diff| reads complete before overwriting with h1

    // h1 = relu(acc + U[b,i] + V[b,j]) -> dbuf (same swizzle)
    {
        const float* Urow = U + bi * ND;
        const float4 ua = *(const float4*)(Urow + c0);
        const float4 ub = *(const float4*)(Urow + c0 + 4);
        #pragma unroll
        for (int r = 0; r < 8; ++r) {
            const float* Vrow = V + (b * NN + j0 + r) * ND;
            const float4 va = *(const float4*)(Vrow + c0);
            const float4 vb = *(const float4*)(Vrow + c0 + 4);
            float4 ha, hb;
            ha.x = fmaxf(acc[r][0] + ua.x + va.x, 0.f);
            ha.y = fmaxf(acc[r][1] + ua.y + va.y, 0.f);
            ha.z = fmaxf(acc[r][2] + ua.z + va.z, 0.f);
            ha.w = fmaxf(acc[r][3] + ua.w + va.w, 0.f);
            hb.x = fmaxf(acc[r][4] + ub.x + vb.x, 0.f);
            hb.y = fmaxf(acc[r][5] + ub.y + vb.y, 0.f);
            hb.z = fmaxf(acc[r][6] + ub.z + vb.z, 0.f);
            hb.w = fmaxf(acc[r][7] + ub.w + vb.w, 0.f);
            *(float4*)(dbuf + (j0 + r) * ND + ((c0    ) ^ fx)) = ha;
            *(float4*)(dbuf + (j0 + r) * ND + ((c0 + 4) ^ fx)) = hb;
        }
    }
    __syncthreads();

    // phase 3: layer 2. wave w covers c in [64w, 64w+64); 8x8 (j,m) tile per lane.
    const int w    = tid >> 6;
    const int lane = tid & 63;
    const int tj2  = lane >> 3;            // 0..7
    const int tm   = lane & 7;             // 0..7
    const int j0b = tj2 * 8, m0 = tm * 8;
    const int fx2 = tj2 << 2;
    float acc2[8][8];
    #pragma unroll
    for (int r = 0; r < 8; ++r)
        #pragma unroll
        for (int q = 0; q < 8; ++q) acc2[r][q] = 0.f;

    for (int c4 = 0; c4 < 64; c4 += 4) {
        const int c  = (w << 6) + c4;
        const int cs = c ^ fx2;
        float4 hv[8];
        #pragma unroll
        for (int r = 0; r < 8; ++r) hv[r] = *(const float4*)(dbuf + (j0b + r) * ND + cs);
        #pragma unroll
        for (int kk = 0; kk < 4; ++kk) {
            const float4 w2a = *(const float4*)(W2 + (c + kk) * 64 + m0);
            const float4 w2b = *(const float4*)(W2 + (c + kk) * 64 + m0 + 4);
            #pragma unroll
            for (int r = 0; r < 8; ++r) {
                const float h = (&hv[r].x)[kk];
                acc2[r][0] = fmaf(h, w2a.x, acc2[r][0]);
                acc2[r][1] = fmaf(h, w2a.y, acc2[r][1]);
                acc2[r][2] = fmaf(h, w2a.z, acc2[r][2]);
                acc2[r][3] = fmaf(h, w2a.w, acc2[r][3]);
                acc2[r][4] = fmaf(h, w2b.x, acc2[r][4]);
                acc2[r][5] = fmaf(h, w2b.y, acc2[r][5]);
                acc2[r][6] = fmaf(h, w2b.z, acc2[r][6]);
                acc2[r][7] = fmaf(h, w2b.w, acc2[r][7]);
            }
        }
    }
    __syncthreads();  // all h1 reads done before overwriting with partials

    #pragma unroll
    for (int r = 0; r < 8; ++r) {
        const float4 pa = make_float4(acc2[r][0], acc2[r][1], acc2[r][2], acc2[r][3]);
        const float4 pb = make_float4(acc2[r][4], acc2[r][5], acc2[r][6], acc2[r][7]);
        *(float4*)(dbuf + (w << 12) + (j0b + r) * 64 + m0)     = pa;
        *(float4*)(dbuf + (w << 12) + (j0b + r) * 64 + m0 + 4) = pb;
    }
    __syncthreads();

    // final: h2 = relu(sum_w partials + b2); score = h2@W3 + b3; penalties; la0
    const int m = lane;
    const float w3v = W3[m];
    const float b2v = b2[m];
    const float b3v = b3[0];
    const float pen_i = (alive_t[bi] < 0.5f) ? PEN : 0.0f;
    #pragma unroll
    for (int t = 0; t < 16; ++t) {
        const int j = (t << 2) + w;
        const int idx = (j << 6) + m;      // == t*256 + tid
        const float s = dbuf[idx] + dbuf[4096 + idx] + dbuf[8192 + idx] + dbuf[12288 + idx];
        float val = fmaxf(s + b2v, 0.0f) * w3v;
        #pragma unroll
        for (int off = 1; off < 64; off <<= 1)
            val += __shfl_xor(val, off, 64);
        if (lane == 0) {
            const float sc = val + b3v;
            const float pj = (alive_t1[b * NN + j] < 0.5f) ? PEN : 0.0f;
            const float sp = sc - pen_i - pj;
            const float la = fminf(fmaxf(sp, -PEN), PEN) / TEMP_;   // = -clip(-sp)/TEMP
            laG[bi * NN + j] = la;
        }
    }
}

// ---------------- K3: Sinkhorn (20 iters) + argmax/matched ----------------
__global__ __launch_bounds__(256)
void k3_sinkhorn(const float* __restrict__ laG, const float* __restrict__ alive_t,
                 const float* __restrict__ alive_t1, float* __restrict__ out)
{
    __shared__ float la[NN * 65];          // pad 65: both passes conflict-free
    const int b = blockIdx.x, tid = threadIdx.x;
    for (int idx = tid; idx < NN * NN; idx += 256)
        la[(idx >> 6) * 65 + (idx & 63)] = laG[b * NN * NN + idx];
    __syncthreads();

    const int g = tid >> 2;                // row/col index 0..63
    const int q = tid & 3;                 // quarter
    for (int it = 0; it < 20; ++it) {
        {   // axis=2: normalize rows (over c)
            float m = -INFINITY;
            #pragma unroll
            for (int t = 0; t < 16; ++t) m = fmaxf(m, la[g * 65 + q * 16 + t]);
            m = fmaxf(m, __shfl_xor(m, 1, 64));
            m = fmaxf(m, __shfl_xor(m, 2, 64));
            float s = 0.f;
            #pragma unroll
            for (int t = 0; t < 16; ++t) s += expf(la[g * 65 + q * 16 + t] - m);
            s += __shfl_xor(s, 1, 64);
            s += __shfl_xor(s, 2, 64);
            const float lse = m + logf(s);
            #pragma unroll
            for (int t = 0; t < 16; ++t) la[g * 65 + q * 16 + t] -= lse;
        }
        __syncthreads();
        {   // axis=1: normalize cols (over r)
            float m = -INFINITY;
            #pragma unroll
            for (int t = 0; t < 16; ++t) m = fmaxf(m, la[(q * 16 + t) * 65 + g]);
            m = fmaxf(m, __shfl_xor(m, 1, 64));
            m = fmaxf(m, __shfl_xor(m, 2, 64));
            float s = 0.f;
            #pragma unroll
            for (int t = 0; t < 16; ++t) s += expf(la[(q * 16 + t) * 65 + g] - m);
            s += __shfl_xor(s, 1, 64);
            s += __shfl_xor(s, 2, 64);
            const float lse = m + logf(s);
            #pragma unroll
            for (int t = 0; t < 16; ++t) la[(q * 16 + t) * 65 + g] -= lse;
        }
        __syncthreads();
    }

    // argmax over axis 2 with first-index tie-break; outputs
    float bm = -INFINITY; int bidx = 0;
    #pragma unroll
    for (int t = 0; t < 16; ++t) {
        const float v = la[g * 65 + q * 16 + t];
        if (v > bm) { bm = v; bidx = q * 16 + t; }
    }
    #pragma unroll
    for (int off = 1; off < 4; off <<= 1) {
        const float om = __shfl_xor(bm, off, 64);
        const int   oi = __shfl_xor(bidx, off, 64);
        if (om > bm || (om == bm && oi < bidx)) { bm = om; bidx = oi; }
    }
    if (q == 0) {
        const float conf = expf(bm);
        const float at  = alive_t[b * NN + g];
        const float at1 = alive_t1[b * NN + bidx];
        const float matched = (at > 0.5f && at1 > 0.5f && conf > 0.3f) ? 1.0f : 0.0f;
        out[b * NN + g] = (float)bidx;                 // perm (written as float)
        out[NB * NN + b * NN + g] = matched;           // matched
    }
}

extern "C" void kernel_launch(void* const* d_in, const int* in_sizes, int n_in,
                              void* d_out, int out_size, void* d_ws, size_t ws_size,
                              hipStream_t stream)
{
    (void)in_sizes; (void)n_in; (void)out_size; (void)ws_size;
    const float* s_t      = (const float*)d_in[0];
    const float* s_t1     = (const float*)d_in[1];
    const float* alive_t  = (const float*)d_in[2];
    const float* alive_t1 = (const float*)d_in[3];
    const float* W1 = (const float*)d_in[4];
    const float* b1 = (const float*)d_in[5];
    const float* W2 = (const float*)d_in[6];
    const float* b2 = (const float*)d_in[7];
    const float* W3 = (const float*)d_in[8];
    const float* b3 = (const float*)d_in[9];

    float* U   = (float*)d_ws;                 // 2048*256
    float* V   = U + NB * NN * ND;             // 2048*256
    float* laG = V + NB * NN * ND;             // 32*64*64
    float* out = (float*)d_out;

    hipLaunchKernelGGL(k1_uv, dim3(256), dim3(256), 0, stream, s_t, s_t1, W1, b1, U, V);
    hipLaunchKernelGGL(k2_scores, dim3(NB * NN), dim3(256), 0, stream,
                       s_t, s_t1, W1, W2, b2, W3, b3, alive_t, alive_t1, U, V, laG);
    hipLaunchKernelGGL(k3_sinkhorn, dim3(NB), dim3(256), 0, stream,
                       laG, alive_t, alive_t1, out);
}

// Round 3
// 401.550 us; speedup vs baseline: 1.0815x; 1.0140x over previous
//
#include <hip/hip_runtime.h>

#define NB 32
#define NN 64
#define ND 256
constexpr float PEN = 10000.0f;
constexpr float TEMP_ = 0.05f;

__device__ __forceinline__ float clip50(float x) { return fminf(fmaxf(x, -50.0f), 50.0f); }

#define FMA_ROW(ar, d, wa, wb) \
    ar[0]=fmaf(d,(wa).x,ar[0]); ar[1]=fmaf(d,(wa).y,ar[1]); \
    ar[2]=fmaf(d,(wa).z,ar[2]); ar[3]=fmaf(d,(wa).w,ar[3]); \
    ar[4]=fmaf(d,(wb).x,ar[4]); ar[5]=fmaf(d,(wb).y,ar[5]); \
    ar[6]=fmaf(d,(wb).z,ar[6]); ar[7]=fmaf(d,(wb).w,ar[7]);

// ---------------- K1: U = clip(s_t)@W1a + b1 ; V = clip(s_t1)@W1b ----------------
// 512 blocks: half = b>>8 (0->U,1->V); 16-row tile x 128-col half per block -> 2 blocks/CU.
__global__ __launch_bounds__(256)
void k1_uv(const float* __restrict__ s_t, const float* __restrict__ s_t1,
           const float* __restrict__ W1, const float* __restrict__ b1,
           float* __restrict__ U, float* __restrict__ V)
{
    const int half = blockIdx.x >> 8;
    const int rem  = blockIdx.x & 255;
    const int rb   = rem >> 1;             // 0..127
    const int colh = rem & 1;              // 0/1
    const int tid  = threadIdx.x;
    const float* src = half ? s_t1 : s_t;
    const float* W   = W1 + half * ND * ND;
    float* dst = half ? V : U;
    __shared__ float sL[16 * ND];
    const int rbase = rb * 16;
    #pragma unroll
    for (int t = 0; t < 4; ++t) {
        const int i4 = ((t << 8) + tid) << 2;
        float4 a = *(const float4*)(src + rbase * ND + i4);
        a.x = clip50(a.x); a.y = clip50(a.y); a.z = clip50(a.z); a.w = clip50(a.w);
        *(float4*)(sL + i4) = a;
    }
    __syncthreads();
    const int wv   = tid >> 6;
    const int lane = tid & 63;
    const int tj1  = lane >> 5;            // 0..1 (2-way LDS alias = free)
    const int tc   = lane & 31;
    const int r0   = wv * 4 + tj1 * 2;     // 2 rows per lane
    const int c0   = colh * 128 + tc * 4;  // 4 cols per lane
    float acc[2][4] = {};
    float4 svS[2][2], wvS[2][4];

    #define K1_LOAD(s, kb) { \
        _Pragma("unroll") for (int r_=0;r_<2;++r_) svS[s][r_] = *(const float4*)(sL + (r0+r_)*ND + (kb)); \
        _Pragma("unroll") for (int kk_=0;kk_<4;++kk_) wvS[s][kk_] = *(const float4*)(W + ((kb)+kk_)*ND + c0); }
    #define K1_FMA(s) { \
        _Pragma("unroll") for (int kk_=0;kk_<4;++kk_) \
        _Pragma("unroll") for (int r_=0;r_<2;++r_) { \
            const float s_ = (&svS[s][r_].x)[kk_]; \
            acc[r_][0]=fmaf(s_,wvS[s][kk_].x,acc[r_][0]); \
            acc[r_][1]=fmaf(s_,wvS[s][kk_].y,acc[r_][1]); \
            acc[r_][2]=fmaf(s_,wvS[s][kk_].z,acc[r_][2]); \
            acc[r_][3]=fmaf(s_,wvS[s][kk_].w,acc[r_][3]); } }

    K1_LOAD(0, 0)
    for (int k4 = 0; k4 < ND; k4 += 8) {
        K1_LOAD(1, k4 + 4)
        K1_FMA(0)
        K1_LOAD(0, (k4 + 8) & (ND - 1))    // wraps to 0 on last iter (unused)
        K1_FMA(1)
    }
    float4 bias = make_float4(0.f, 0.f, 0.f, 0.f);
    if (!half) bias = *(const float4*)(b1 + c0);
    #pragma unroll
    for (int r = 0; r < 2; ++r) {
        float4 o;
        o.x = acc[r][0] + bias.x; o.y = acc[r][1] + bias.y;
        o.z = acc[r][2] + bias.z; o.w = acc[r][3] + bias.w;
        *(float4*)(dst + (rbase + r0 + r) * ND + c0) = o;
    }
}

// ---------------- K2: per-(b,i) pair-MLP -> initial log_alpha row ----------------
// Unified lane map for GEMM phases: w = tid>>6 (64-col slice), tj = (tid&63)>>3
// (8-row group), tm = tid&7 (8-col group). Each block reads W1c exactly once.
// Swizzle: element (row j, col k) at j*256 + (k ^ (4*(j>>3))).
__global__ __launch_bounds__(256, 2)
void k2_scores(const float* __restrict__ s_t, const float* __restrict__ s_t1,
               const float* __restrict__ W1, const float* __restrict__ W2,
               const float* __restrict__ b2, const float* __restrict__ W3,
               const float* __restrict__ b3, const float* __restrict__ alive_t,
               const float* __restrict__ alive_t1,
               const float* __restrict__ U, const float* __restrict__ V,
               float* __restrict__ laG)
{
    __shared__ float dbuf[NN * ND];
    const int tid = threadIdx.x;
    const int bi  = blockIdx.x;            // b*64 + i
    const int b   = bi >> 6;

    // phase 1: fill |diff| (swizzled), float4 end-to-end.
    {
        const float* stb = s_t + bi * ND;
        const float* s1b = s_t1 + b * NN * ND;
        #pragma unroll
        for (int t = 0; t < 16; ++t) {
            const int idx = (t << 8) + tid;
            const int j   = idx >> 6;
            const int c4  = (idx & 63) << 2;
            const float4 a  = *(const float4*)(stb + c4);
            const float4 v1 = *(const float4*)(s1b + j * ND + c4);
            float4 d;
            d.x = fabsf(clip50(a.x) - clip50(v1.x));
            d.y = fabsf(clip50(a.y) - clip50(v1.y));
            d.z = fabsf(clip50(a.z) - clip50(v1.z));
            d.w = fabsf(clip50(a.w) - clip50(v1.w));
            *(float4*)(dbuf + j * ND + (c4 ^ ((j >> 3) << 2))) = d;
        }
    }
    __syncthreads();

    const int lane = tid & 63;
    const int w    = tid >> 6;             // c-slice [64w, 64w+64)
    const int tj   = lane >> 3;            // 0..7
    const int tm   = lane & 7;             // 0..7
    const int j0   = tj << 3;
    const int fx   = tj << 2;
    const int cb   = (w << 6) + (tm << 3); // this lane's 8 output cols
    const float* W1c = W1 + 2 * ND * ND;

    // phase 2: layer 1 pairwise: acc[r][q] = sum_k d[j0+r][k] * W1c[k][cb+q]
    float acc[8][8] = {};
    {
        float4 dvS[2][8], wS[2][4][2];
        #define K2_LOAD1(s, kb) { \
            const int ks_ = (kb) ^ fx; \
            _Pragma("unroll") for (int r_=0;r_<8;++r_) dvS[s][r_] = *(const float4*)(dbuf + (j0+r_)*ND + ks_); \
            _Pragma("unroll") for (int kk_=0;kk_<4;++kk_) { \
                wS[s][kk_][0] = *(const float4*)(W1c + ((kb)+kk_)*ND + cb); \
                wS[s][kk_][1] = *(const float4*)(W1c + ((kb)+kk_)*ND + cb + 4); } }
        #define K2_FMA1(s) { \
            _Pragma("unroll") for (int kk_=0;kk_<4;++kk_) \
            _Pragma("unroll") for (int r_=0;r_<8;++r_) { \
                const float d_ = (&dvS[s][r_].x)[kk_]; \
                FMA_ROW(acc[r_], d_, wS[s][kk_][0], wS[s][kk_][1]) } }
        K2_LOAD1(0, 0)
        for (int k4 = 0; k4 < ND; k4 += 8) {
            K2_LOAD1(1, k4 + 4)
            K2_FMA1(0)
            K2_LOAD1(0, (k4 + 8) & (ND - 1))   // harmless wrap on last iter
            K2_FMA1(1)
        }
    }
    __syncthreads();   // all |diff| reads done before h1 overwrites dbuf

    // h1 = relu(acc + U[b,i] + V[b,j]) -> dbuf (same swizzle). Each wave writes
    // exactly the columns it will read in phase 3 -> no barrier needed after.
    {
        const float4 ua = *(const float4*)(U + bi * ND + cb);
        const float4 ub = *(const float4*)(U + bi * ND + cb + 4);
        const int wbc = cb ^ fx;
        #pragma unroll
        for (int r = 0; r < 8; ++r) {
            const float* Vrow = V + (b * NN + j0 + r) * ND;
            const float4 va = *(const float4*)(Vrow + cb);
            const float4 vb = *(const float4*)(Vrow + cb + 4);
            float4 ha, hb;
            ha.x = fmaxf(acc[r][0] + ua.x + va.x, 0.f);
            ha.y = fmaxf(acc[r][1] + ua.y + va.y, 0.f);
            ha.z = fmaxf(acc[r][2] + ua.z + va.z, 0.f);
            ha.w = fmaxf(acc[r][3] + ua.w + va.w, 0.f);
            hb.x = fmaxf(acc[r][4] + ub.x + vb.x, 0.f);
            hb.y = fmaxf(acc[r][5] + ub.y + vb.y, 0.f);
            hb.z = fmaxf(acc[r][6] + ub.z + vb.z, 0.f);
            hb.w = fmaxf(acc[r][7] + ub.w + vb.w, 0.f);
            *(float4*)(dbuf + (j0 + r) * ND + wbc)       = ha;
            *(float4*)(dbuf + (j0 + r) * ND + (wbc ^ 4)) = hb;
        }
    }

    // phase 3: layer 2 over this wave's c-slice; lane tile 8j x 8m.
    float acc2[8][8] = {};
    {
        const int m8 = tm << 3;
        const int cw = w << 6;
        float4 hvS[2][8], w2S[2][4][2];
        #define K2_LOAD3(s, cb_) { \
            const int cs_ = (cb_) ^ fx; \
            _Pragma("unroll") for (int r_=0;r_<8;++r_) hvS[s][r_] = *(const float4*)(dbuf + (j0+r_)*ND + cs_); \
            _Pragma("unroll") for (int kk_=0;kk_<4;++kk_) { \
                w2S[s][kk_][0] = *(const float4*)(W2 + ((cb_)+kk_)*64 + m8); \
                w2S[s][kk_][1] = *(const float4*)(W2 + ((cb_)+kk_)*64 + m8 + 4); } }
        #define K2_FMA3(s) { \
            _Pragma("unroll") for (int kk_=0;kk_<4;++kk_) \
            _Pragma("unroll") for (int r_=0;r_<8;++r_) { \
                const float h_ = (&hvS[s][r_].x)[kk_]; \
                FMA_ROW(acc2[r_], h_, w2S[s][kk_][0], w2S[s][kk_][1]) } }
        K2_LOAD3(0, cw)
        for (int c4 = 0; c4 < 64; c4 += 8) {
            K2_LOAD3(1, cw + c4 + 4)
            K2_FMA3(0)
            K2_LOAD3(0, cw + ((c4 + 8) & 63))  // harmless wrap on last iter
            K2_FMA3(1)
        }
    }
    __syncthreads();   // all h1 reads done before partials overwrite dbuf

    // partials store, XOR-swizzled: element (w,j,m) at (w<<12)+(j<<6)+(m^(4*(j>>3))).
    {
        const int m8 = tm << 3;
        const int pc = m8 ^ fx;
        #pragma unroll
        for (int r = 0; r < 8; ++r) {
            const float4 pa = make_float4(acc2[r][0], acc2[r][1], acc2[r][2], acc2[r][3]);
            const float4 pb = make_float4(acc2[r][4], acc2[r][5], acc2[r][6], acc2[r][7]);
            *(float4*)(dbuf + (w << 12) + ((j0 + r) << 6) + pc)       = pa;
            *(float4*)(dbuf + (w << 12) + ((j0 + r) << 6) + (pc ^ 4)) = pb;
        }
    }
    __syncthreads();

    // final: h2 = relu(sum_w partials + b2); score = h2@W3 + b3; penalties; la0
    const float w3v = W3[lane];            // m == lane
    const float b2v = b2[lane];
    const float b3v = b3[0];
    const float pen_i = (alive_t[bi] < 0.5f) ? PEN : 0.0f;
    #pragma unroll
    for (int t = 0; t < 16; ++t) {
        const int j   = (t << 2) + w;
        const int fxj = (j >> 3) << 2;
        const int idx = (j << 6) + (lane ^ fxj);   // element m = lane
        const float s = dbuf[idx] + dbuf[4096 + idx] + dbuf[8192 + idx] + dbuf[12288 + idx];
        float val = fmaxf(s + b2v, 0.0f) * w3v;
        #pragma unroll
        for (int off = 1; off < 64; off <<= 1)
            val += __shfl_xor(val, off, 64);
        if (lane == 0) {
            const float sc = val + b3v;
            const float pj = (alive_t1[b * NN + j] < 0.5f) ? PEN : 0.0f;
            const float sp = sc - pen_i - pj;
            const float la = fminf(fmaxf(sp, -PEN), PEN) / TEMP_;   // = -clip(-sp)/TEMP
            laG[bi * NN + j] = la;
        }
    }
}

// ---------------- K3: Sinkhorn (20 iters) + argmax/matched ----------------
__global__ __launch_bounds__(256)
void k3_sinkhorn(const float* __restrict__ laG, const float* __restrict__ alive_t,
                 const float* __restrict__ alive_t1, float* __restrict__ out)
{
    __shared__ float la[NN * 65];          // pad 65: both passes conflict-free
    const int b = blockIdx.x, tid = threadIdx.x;
    for (int idx = tid; idx < NN * NN; idx += 256)
        la[(idx >> 6) * 65 + (idx & 63)] = laG[b * NN * NN + idx];
    __syncthreads();

    const int g = tid >> 2;                // row/col index 0..63
    const int q = tid & 3;                 // quarter
    for (int it = 0; it < 20; ++it) {
        {   // axis=2: normalize rows (over c)
            float m = -INFINITY;
            #pragma unroll
            for (int t = 0; t < 16; ++t) m = fmaxf(m, la[g * 65 + q * 16 + t]);
            m = fmaxf(m, __shfl_xor(m, 1, 64));
            m = fmaxf(m, __shfl_xor(m, 2, 64));
            float s = 0.f;
            #pragma unroll
            for (int t = 0; t < 16; ++t) s += expf(la[g * 65 + q * 16 + t] - m);
            s += __shfl_xor(s, 1, 64);
            s += __shfl_xor(s, 2, 64);
            const float lse = m + logf(s);
            #pragma unroll
            for (int t = 0; t < 16; ++t) la[g * 65 + q * 16 + t] -= lse;
        }
        __syncthreads();
        {   // axis=1: normalize cols (over r)
            float m = -INFINITY;
            #pragma unroll
            for (int t = 0; t < 16; ++t) m = fmaxf(m, la[(q * 16 + t) * 65 + g]);
            m = fmaxf(m, __shfl_xor(m, 1, 64));
            m = fmaxf(m, __shfl_xor(m, 2, 64));
            float s = 0.f;
            #pragma unroll
            for (int t = 0; t < 16; ++t) s += expf(la[(q * 16 + t) * 65 + g] - m);
            s += __shfl_xor(s, 1, 64);
            s += __shfl_xor(s, 2, 64);
            const float lse = m + logf(s);
            #pragma unroll
            for (int t = 0; t < 16; ++t) la[(q * 16 + t) * 65 + g] -= lse;
        }
        __syncthreads();
    }

    // argmax over axis 2 with first-index tie-break; outputs
    float bm = -INFINITY; int bidx = 0;
    #pragma unroll
    for (int t = 0; t < 16; ++t) {
        const float v = la[g * 65 + q * 16 + t];
        if (v > bm) { bm = v; bidx = q * 16 + t; }
    }
    #pragma unroll
    for (int off = 1; off < 4; off <<= 1) {
        const float om = __shfl_xor(bm, off, 64);
        const int   oi = __shfl_xor(bidx, off, 64);
        if (om > bm || (om == bm && oi < bidx)) { bm = om; bidx = oi; }
    }
    if (q == 0) {
        const float conf = expf(bm);
        const float at  = alive_t[b * NN + g];
        const float at1 = alive_t1[b * NN + bidx];
        const float matched = (at > 0.5f && at1 > 0.5f && conf > 0.3f) ? 1.0f : 0.0f;
        out[b * NN + g] = (float)bidx;                 // perm (written as float)
        out[NB * NN + b * NN + g] = matched;           // matched
    }
}

extern "C" void kernel_launch(void* const* d_in, const int* in_sizes, int n_in,
                              void* d_out, int out_size, void* d_ws, size_t ws_size,
                              hipStream_t stream)
{
    (void)in_sizes; (void)n_in; (void)out_size; (void)ws_size;
    const float* s_t      = (const float*)d_in[0];
    const float* s_t1     = (const float*)d_in[1];
    const float* alive_t  = (const float*)d_in[2];
    const float* alive_t1 = (const float*)d_in[3];
    const float* W1 = (const float*)d_in[4];
    const float* b1 = (const float*)d_in[5];
    const float* W2 = (const float*)d_in[6];
    const float* b2 = (const float*)d_in[7];
    const float* W3 = (const float*)d_in[8];
    const float* b3 = (const float*)d_in[9];

    float* U   = (float*)d_ws;                 // 2048*256
    float* V   = U + NB * NN * ND;             // 2048*256
    float* laG = V + NB * NN * ND;             // 32*64*64
    float* out = (float*)d_out;

    hipLaunchKernelGGL(k1_uv, dim3(512), dim3(256), 0, stream, s_t, s_t1, W1, b1, U, V);
    hipLaunchKernelGGL(k2_scores, dim3(NB * NN), dim3(256), 0, stream,
                       s_t, s_t1, W1, W2, b2, W3, b3, alive_t, alive_t1, U, V, laG);
    hipLaunchKernelGGL(k3_sinkhorn, dim3(NB), dim3(256), 0, stream,
                       laG, alive_t, alive_t1, out);
}

// Round 4
// 208.930 us; speedup vs baseline: 2.0785x; 1.9219x over previous
//
#include <hip/hip_runtime.h>

#define NB 32
#define NN 64
#define ND 256
constexpr float PEN = 10000.0f;
constexpr float TEMP_ = 0.05f;

typedef __bf16 bfrag __attribute__((ext_vector_type(8)));   // 8 bf16 = 4 VGPR (MFMA A/B)
typedef float  f32x4 __attribute__((ext_vector_type(4)));   // MFMA C/D

__device__ __forceinline__ float clip50(float x) { return fminf(fmaxf(x, -50.0f), 50.0f); }

// round-to-nearest-even f32 -> bf16 bit pattern (inputs never NaN here)
__device__ __forceinline__ ushort bf16_rne(float x) {
    uint u = __builtin_bit_cast(uint, x);
    return (ushort)((u + 0x7fffu + ((u >> 16) & 1u)) >> 16);
}
// split x = hi + lo (both bf16), packed pairwise into uints
__device__ __forceinline__ void split2(float a, float b, uint& h, uint& l) {
    const ushort ha = bf16_rne(a), hb = bf16_rne(b);
    const float fa = __builtin_bit_cast(float, (uint)ha << 16);
    const float fb = __builtin_bit_cast(float, (uint)hb << 16);
    const ushort la = bf16_rne(a - fa), lb = bf16_rne(b - fb);
    h = (uint)ha | ((uint)hb << 16);
    l = (uint)la | ((uint)lb << 16);
}
// LDS A-plane swizzle: element (row m, col k) bf16 at byte m*512 + (2k ^ ((m&7)<<4))
#define ASW(m, k2) ((m) * 512 + ((k2) ^ (((m) & 7) << 4)))

// ---------------- K01: U/V GEMMs (blocks 0..511) + W-pack (blocks 512..551) ----
__global__ __launch_bounds__(256)
void k01_uv_pack(const float* __restrict__ s_t, const float* __restrict__ s_t1,
                 const float* __restrict__ W1, const float* __restrict__ b1,
                 const float* __restrict__ W2, float* __restrict__ U,
                 float* __restrict__ V, ushort* __restrict__ w1h,
                 ushort* __restrict__ w1l, ushort* __restrict__ w2h,
                 ushort* __restrict__ w2l)
{
    const int tid = threadIdx.x;
    if (blockIdx.x >= 512) {
        // ---- pack W1c (8192 threads) and W2 (2048 threads) into B-frag order ----
        const int gid = (blockIdx.x - 512) * 256 + tid;
        const float* srcW; ushort *dh, *dl;
        int fb, kt, col, kbase, stride, base;
        if (gid < 8192) {            // W1c: frag blocks fb = kt*16 + ntg, kt<8, ntg<16
            fb = gid >> 6; kt = fb >> 4;
            const int ntg = fb & 15, ln = gid & 63;
            col = ntg * 16 + (ln & 15); kbase = kt * 32 + (ln >> 4) * 8;
            srcW = W1 + 2 * ND * ND; stride = ND; dh = w1h; dl = w1l; base = gid * 8;
        } else {                     // W2: fb = kt*4 + ntg, kt<8, ntg<4
            const int g2 = gid - 8192;
            fb = g2 >> 6; kt = fb >> 2;
            const int ntg = fb & 3, ln = g2 & 63;
            col = ntg * 16 + (ln & 15); kbase = kt * 32 + (ln >> 4) * 8;
            srcW = W2; stride = 64; dh = w2h; dl = w2l; base = g2 * 8;
        }
        uint hv[4], lv[4];
        #pragma unroll
        for (int p = 0; p < 4; ++p) {
            const float a = srcW[(kbase + 2 * p) * stride + col];
            const float b = srcW[(kbase + 2 * p + 1) * stride + col];
            split2(a, b, hv[p], lv[p]);
        }
        *(uint4*)(dh + base) = make_uint4(hv[0], hv[1], hv[2], hv[3]);
        *(uint4*)(dl + base) = make_uint4(lv[0], lv[1], lv[2], lv[3]);
        return;
    }
    // ---- U/V: 512 blocks, 16-row x 128-col tiles (fp32 exact) ----
    const int half = blockIdx.x >> 8;
    const int rem  = blockIdx.x & 255;
    const int rb   = rem >> 1;
    const int colh = rem & 1;
    const float* src = half ? s_t1 : s_t;
    const float* W   = W1 + half * ND * ND;
    float* dst = half ? V : U;
    __shared__ float sL[16 * ND];
    const int rbase = rb * 16;
    #pragma unroll
    for (int t = 0; t < 4; ++t) {
        const int i4 = ((t << 8) + tid) << 2;
        float4 a = *(const float4*)(src + rbase * ND + i4);
        a.x = clip50(a.x); a.y = clip50(a.y); a.z = clip50(a.z); a.w = clip50(a.w);
        *(float4*)(sL + i4) = a;
    }
    __syncthreads();
    const int wv   = tid >> 6;
    const int lane = tid & 63;
    const int tj1  = lane >> 5;
    const int tc   = lane & 31;
    const int r0   = wv * 4 + tj1 * 2;
    const int c0   = colh * 128 + tc * 4;
    float acc[2][4] = {};
    for (int k4 = 0; k4 < ND; k4 += 4) {
        float4 sv[2];
        #pragma unroll
        for (int r = 0; r < 2; ++r) sv[r] = *(const float4*)(sL + (r0 + r) * ND + k4);
        #pragma unroll
        for (int kk = 0; kk < 4; ++kk) {
            const float4 wvv = *(const float4*)(W + (k4 + kk) * ND + c0);
            #pragma unroll
            for (int r = 0; r < 2; ++r) {
                const float s = (&sv[r].x)[kk];
                acc[r][0] = fmaf(s, wvv.x, acc[r][0]);
                acc[r][1] = fmaf(s, wvv.y, acc[r][1]);
                acc[r][2] = fmaf(s, wvv.z, acc[r][2]);
                acc[r][3] = fmaf(s, wvv.w, acc[r][3]);
            }
        }
    }
    float4 bias = make_float4(0.f, 0.f, 0.f, 0.f);
    if (!half) bias = *(const float4*)(b1 + c0);
    #pragma unroll
    for (int r = 0; r < 2; ++r) {
        float4 o;
        o.x = acc[r][0] + bias.x; o.y = acc[r][1] + bias.y;
        o.z = acc[r][2] + bias.z; o.w = acc[r][3] + bias.w;
        *(float4*)(dst + (rbase + r0 + r) * ND + c0) = o;
    }
}

// ---------------- K2: per-(b,i) pair-MLP via split-bf16 MFMA ----------------
// LDS planes sAh/sAl hold A-operand (bf16 hi/lo): first |diff| (64x256), then h1.
// Wave w owns output cols [64w, 64w+64). 16x16x32 MFMA, layouts per guide:
//   A: m=lane&15, k=(lane>>4)*8+j ; C/D: col=lane&15, row=(lane>>4)*4+reg.
__global__ __launch_bounds__(256, 2)
void k2_scores(const float* __restrict__ s_t, const float* __restrict__ s_t1,
               const float* __restrict__ b2, const float* __restrict__ W3,
               const float* __restrict__ b3, const float* __restrict__ alive_t,
               const float* __restrict__ alive_t1,
               const float* __restrict__ U, const float* __restrict__ V,
               const ushort* __restrict__ w1h, const ushort* __restrict__ w1l,
               const ushort* __restrict__ w2h, const ushort* __restrict__ w2l,
               float* __restrict__ laG)
{
    __shared__ ushort sAh[NN * ND];    // 32 KB
    __shared__ ushort sAl[NN * ND];    // 32 KB
    __shared__ float  red[4 * NN];     // 1 KB
    const int tid = threadIdx.x;
    const int bi  = blockIdx.x;
    const int b   = bi >> 6;
    const int lane = tid & 63;
    const int w    = tid >> 6;
    const int mlane = lane & 15;       // frag row/col within tile
    const int kg    = lane >> 4;       // k-group 0..3

    // ---- phase 1: diff = |clip(s_t[i]) - clip(s_t1[j])| -> hi/lo LDS planes ----
    {
        const float* stb = s_t + bi * ND;
        const float* s1b = s_t1 + (size_t)b * NN * ND;
        #pragma unroll
        for (int t = 0; t < 8; ++t) {
            const int slot = (t << 8) + tid;       // 2048 slots of 8 k
            const int m  = slot >> 5;
            const int k0 = (slot & 31) << 3;
            const float4 a0 = *(const float4*)(stb + k0);
            const float4 a1 = *(const float4*)(stb + k0 + 4);
            const float4 p0 = *(const float4*)(s1b + m * ND + k0);
            const float4 p1 = *(const float4*)(s1b + m * ND + k0 + 4);
            float d[8];
            d[0] = fabsf(clip50(a0.x) - clip50(p0.x));
            d[1] = fabsf(clip50(a0.y) - clip50(p0.y));
            d[2] = fabsf(clip50(a0.z) - clip50(p0.z));
            d[3] = fabsf(clip50(a0.w) - clip50(p0.w));
            d[4] = fabsf(clip50(a1.x) - clip50(p1.x));
            d[5] = fabsf(clip50(a1.y) - clip50(p1.y));
            d[6] = fabsf(clip50(a1.z) - clip50(p1.z));
            d[7] = fabsf(clip50(a1.w) - clip50(p1.w));
            uint hv[4], lv[4];
            #pragma unroll
            for (int p = 0; p < 4; ++p) split2(d[2*p], d[2*p+1], hv[p], lv[p]);
            const int off = ASW(m, k0 * 2);
            *(uint4*)((char*)sAh + off) = make_uint4(hv[0], hv[1], hv[2], hv[3]);
            *(uint4*)((char*)sAl + off) = make_uint4(lv[0], lv[1], lv[2], lv[3]);
        }
    }
    __syncthreads();

    // ---- phase 2: C1 = diff @ W1c  (M=64, N=64 per wave, K=256) ----
    f32x4 acc[4][4];
    #pragma unroll
    for (int mt = 0; mt < 4; ++mt)
        #pragma unroll
        for (int nt = 0; nt < 4; ++nt)
            #pragma unroll
            for (int r = 0; r < 4; ++r) acc[mt][nt][r] = 0.f;
    #pragma unroll
    for (int kt = 0; kt < 8; ++kt) {
        bfrag Bh[4], Bl[4], Ah[4], Al[4];
        #pragma unroll
        for (int nt = 0; nt < 4; ++nt) {
            const int fo = (kt * 16 + (w << 2) + nt) * 512 + lane * 8;
            Bh[nt] = *(const bfrag*)(w1h + fo);
            Bl[nt] = *(const bfrag*)(w1l + fo);
        }
        const int k2b = (kt * 32 + kg * 8) * 2;
        #pragma unroll
        for (int mt = 0; mt < 4; ++mt) {
            const int m = mt * 16 + mlane;
            const int off = ASW(m, k2b);
            Ah[mt] = *(const bfrag*)((const char*)sAh + off);
            Al[mt] = *(const bfrag*)((const char*)sAl + off);
        }
        #pragma unroll
        for (int mt = 0; mt < 4; ++mt)
            #pragma unroll
            for (int nt = 0; nt < 4; ++nt) {
                acc[mt][nt] = __builtin_amdgcn_mfma_f32_16x16x32_bf16(Ah[mt], Bh[nt], acc[mt][nt], 0, 0, 0);
                acc[mt][nt] = __builtin_amdgcn_mfma_f32_16x16x32_bf16(Ah[mt], Bl[nt], acc[mt][nt], 0, 0, 0);
                acc[mt][nt] = __builtin_amdgcn_mfma_f32_16x16x32_bf16(Al[mt], Bh[nt], acc[mt][nt], 0, 0, 0);
            }
    }
    __syncthreads();   // all phase-2 A reads done before h1 overwrites planes

    // ---- epilogue: h1 = relu(C1 + U[bi,c] + V[b,j,c]) -> hi/lo planes ----
    {
        const float* Ur = U + (size_t)bi * ND;
        const float* Vb = V + (size_t)b * NN * ND;
        float Uc[4];
        #pragma unroll
        for (int nt = 0; nt < 4; ++nt) Uc[nt] = Ur[w * 64 + nt * 16 + mlane];
        #pragma unroll
        for (int mt = 0; mt < 4; ++mt) {
            #pragma unroll
            for (int r = 0; r < 4; ++r) {
                const int j = mt * 16 + (kg << 2) + r;
                const float* Vr = Vb + (size_t)j * ND;
                #pragma unroll
                for (int nt = 0; nt < 4; ++nt) {
                    const int c = w * 64 + nt * 16 + mlane;
                    float x = acc[mt][nt][r] + Uc[nt] + Vr[c];
                    x = fmaxf(x, 0.f);
                    const ushort hh = bf16_rne(x);
                    const float  fh = __builtin_bit_cast(float, (uint)hh << 16);
                    const ushort ll = bf16_rne(x - fh);
                    const int off = ASW(j, c * 2);
                    *(ushort*)((char*)sAh + off) = hh;
                    *(ushort*)((char*)sAl + off) = ll;
                }
            }
        }
    }
    __syncthreads();

    // ---- phase 3: C2 = h1 @ W2 (wave w -> N-tile w, all 4 M-tiles) ----
    f32x4 acc2[4];
    #pragma unroll
    for (int mt = 0; mt < 4; ++mt)
        #pragma unroll
        for (int r = 0; r < 4; ++r) acc2[mt][r] = 0.f;
    #pragma unroll
    for (int kt = 0; kt < 8; ++kt) {
        const int fo = (kt * 4 + w) * 512 + lane * 8;
        const bfrag Bh = *(const bfrag*)(w2h + fo);
        const bfrag Bl = *(const bfrag*)(w2l + fo);
        const int k2b = (kt * 32 + kg * 8) * 2;
        #pragma unroll
        for (int mt = 0; mt < 4; ++mt) {
            const int m = mt * 16 + mlane;
            const int off = ASW(m, k2b);
            const bfrag Ah = *(const bfrag*)((const char*)sAh + off);
            const bfrag Al = *(const bfrag*)((const char*)sAl + off);
            acc2[mt] = __builtin_amdgcn_mfma_f32_16x16x32_bf16(Ah, Bh, acc2[mt], 0, 0, 0);
            acc2[mt] = __builtin_amdgcn_mfma_f32_16x16x32_bf16(Ah, Bl, acc2[mt], 0, 0, 0);
            acc2[mt] = __builtin_amdgcn_mfma_f32_16x16x32_bf16(Al, Bh, acc2[mt], 0, 0, 0);
        }
    }

    // ---- final: h2 = relu(C2 + b2); partial score = sum_m h2*W3 ----
    {
        const int m = w * 16 + mlane;
        const float b2v = b2[m];
        const float w3v = W3[m];
        #pragma unroll
        for (int mt = 0; mt < 4; ++mt) {
            #pragma unroll
            for (int r = 0; r < 4; ++r) {
                const int j = mt * 16 + (kg << 2) + r;
                float val = fmaxf(acc2[mt][r] + b2v, 0.f) * w3v;
                val += __shfl_xor(val, 1, 64);
                val += __shfl_xor(val, 2, 64);
                val += __shfl_xor(val, 4, 64);
                val += __shfl_xor(val, 8, 64);
                if (mlane == 0) red[w * NN + j] = val;
            }
        }
    }
    __syncthreads();
    if (tid < NN) {
        const int j = tid;
        const float sc = red[j] + red[NN + j] + red[2 * NN + j] + red[3 * NN + j] + b3[0];
        const float pen_i = (alive_t[bi] < 0.5f) ? PEN : 0.0f;
        const float pj = (alive_t1[b * NN + j] < 0.5f) ? PEN : 0.0f;
        const float sp = sc - pen_i - pj;
        laG[bi * NN + j] = fminf(fmaxf(sp, -PEN), PEN) / TEMP_;
    }
}

// ---------------- K3: Sinkhorn (20 iters) + argmax/matched ----------------
__global__ __launch_bounds__(256)
void k3_sinkhorn(const float* __restrict__ laG, const float* __restrict__ alive_t,
                 const float* __restrict__ alive_t1, float* __restrict__ out)
{
    __shared__ float la[NN * 65];
    const int b = blockIdx.x, tid = threadIdx.x;
    for (int idx = tid; idx < NN * NN; idx += 256)
        la[(idx >> 6) * 65 + (idx & 63)] = laG[b * NN * NN + idx];
    __syncthreads();

    const int g = tid >> 2;
    const int q = tid & 3;
    for (int it = 0; it < 20; ++it) {
        {
            float m = -INFINITY;
            #pragma unroll
            for (int t = 0; t < 16; ++t) m = fmaxf(m, la[g * 65 + q * 16 + t]);
            m = fmaxf(m, __shfl_xor(m, 1, 64));
            m = fmaxf(m, __shfl_xor(m, 2, 64));
            float s = 0.f;
            #pragma unroll
            for (int t = 0; t < 16; ++t) s += expf(la[g * 65 + q * 16 + t] - m);
            s += __shfl_xor(s, 1, 64);
            s += __shfl_xor(s, 2, 64);
            const float lse = m + logf(s);
            #pragma unroll
            for (int t = 0; t < 16; ++t) la[g * 65 + q * 16 + t] -= lse;
        }
        __syncthreads();
        {
            float m = -INFINITY;
            #pragma unroll
            for (int t = 0; t < 16; ++t) m = fmaxf(m, la[(q * 16 + t) * 65 + g]);
            m = fmaxf(m, __shfl_xor(m, 1, 64));
            m = fmaxf(m, __shfl_xor(m, 2, 64));
            float s = 0.f;
            #pragma unroll
            for (int t = 0; t < 16; ++t) s += expf(la[(q * 16 + t) * 65 + g] - m);
            s += __shfl_xor(s, 1, 64);
            s += __shfl_xor(s, 2, 64);
            const float lse = m + logf(s);
            #pragma unroll
            for (int t = 0; t < 16; ++t) la[(q * 16 + t) * 65 + g] -= lse;
        }
        __syncthreads();
    }

    float bm = -INFINITY; int bidx = 0;
    #pragma unroll
    for (int t = 0; t < 16; ++t) {
        const float v = la[g * 65 + q * 16 + t];
        if (v > bm) { bm = v; bidx = q * 16 + t; }
    }
    #pragma unroll
    for (int off = 1; off < 4; off <<= 1) {
        const float om = __shfl_xor(bm, off, 64);
        const int   oi = __shfl_xor(bidx, off, 64);
        if (om > bm || (om == bm && oi < bidx)) { bm = om; bidx = oi; }
    }
    if (q == 0) {
        const float conf = expf(bm);
        const float at  = alive_t[b * NN + g];
        const float at1 = alive_t1[b * NN + bidx];
        const float matched = (at > 0.5f && at1 > 0.5f && conf > 0.3f) ? 1.0f : 0.0f;
        out[b * NN + g] = (float)bidx;
        out[NB * NN + b * NN + g] = matched;
    }
}

extern "C" void kernel_launch(void* const* d_in, const int* in_sizes, int n_in,
                              void* d_out, int out_size, void* d_ws, size_t ws_size,
                              hipStream_t stream)
{
    (void)in_sizes; (void)n_in; (void)out_size; (void)ws_size;
    const float* s_t      = (const float*)d_in[0];
    const float* s_t1     = (const float*)d_in[1];
    const float* alive_t  = (const float*)d_in[2];
    const float* alive_t1 = (const float*)d_in[3];
    const float* W1 = (const float*)d_in[4];
    const float* b1 = (const float*)d_in[5];
    const float* W2 = (const float*)d_in[6];
    const float* b2 = (const float*)d_in[7];
    const float* W3 = (const float*)d_in[8];
    const float* b3 = (const float*)d_in[9];

    char* ws = (char*)d_ws;
    float*  U   = (float*)(ws);                         // 2 MB
    float*  V   = (float*)(ws + 2097152);               // 2 MB
    float*  laG = (float*)(ws + 4194304);               // 512 KB
    ushort* w1h = (ushort*)(ws + 4718592);              // 128 KB
    ushort* w1l = (ushort*)(ws + 4849664);              // 128 KB
    ushort* w2h = (ushort*)(ws + 4980736);              // 32 KB
    ushort* w2l = (ushort*)(ws + 5013504);              // 32 KB
    float* out = (float*)d_out;

    hipLaunchKernelGGL(k01_uv_pack, dim3(552), dim3(256), 0, stream,
                       s_t, s_t1, W1, b1, W2, U, V, w1h, w1l, w2h, w2l);
    hipLaunchKernelGGL(k2_scores, dim3(NB * NN), dim3(256), 0, stream,
                       s_t, s_t1, b2, W3, b3, alive_t, alive_t1, U, V,
                       w1h, w1l, w2h, w2l, laG);
    hipLaunchKernelGGL(k3_sinkhorn, dim3(NB), dim3(256), 0, stream,
                       laG, alive_t, alive_t1, out);
}

// Round 5
// 207.685 us; speedup vs baseline: 2.0910x; 1.0060x over previous
//
#include <hip/hip_runtime.h>

#define NB 32
#define NN 64
#define ND 256
#define MH 32   // rows (j) per k2 block after M-split
constexpr float PEN = 10000.0f;
constexpr float TEMP_ = 0.05f;

typedef __bf16 bfrag __attribute__((ext_vector_type(8)));   // 8 bf16 = 4 VGPR (MFMA A/B)
typedef float  f32x4 __attribute__((ext_vector_type(4)));   // MFMA C/D

__device__ __forceinline__ float clip50(float x) { return fminf(fmaxf(x, -50.0f), 50.0f); }

// round-to-nearest-even f32 -> bf16 bit pattern (inputs never NaN here)
__device__ __forceinline__ ushort bf16_rne(float x) {
    uint u = __builtin_bit_cast(uint, x);
    return (ushort)((u + 0x7fffu + ((u >> 16) & 1u)) >> 16);
}
// split x = hi + lo (both bf16), packed pairwise into uints
__device__ __forceinline__ void split2(float a, float b, uint& h, uint& l) {
    const ushort ha = bf16_rne(a), hb = bf16_rne(b);
    const float fa = __builtin_bit_cast(float, (uint)ha << 16);
    const float fb = __builtin_bit_cast(float, (uint)hb << 16);
    const ushort la = bf16_rne(a - fa), lb = bf16_rne(b - fb);
    h = (uint)ha | ((uint)hb << 16);
    l = (uint)la | ((uint)lb << 16);
}
// LDS A-plane swizzle: element (row m, col k) bf16 at byte m*512 + (2k ^ ((m&7)<<4))
#define ASW(m, k2) ((m) * 512 + ((k2) ^ (((m) & 7) << 4)))

// ---------------- K01: U/V GEMMs (blocks 0..511) + W-pack (blocks 512..551) ----
__global__ __launch_bounds__(256)
void k01_uv_pack(const float* __restrict__ s_t, const float* __restrict__ s_t1,
                 const float* __restrict__ W1, const float* __restrict__ b1,
                 const float* __restrict__ W2, float* __restrict__ U,
                 float* __restrict__ V, ushort* __restrict__ w1h,
                 ushort* __restrict__ w1l, ushort* __restrict__ w2h,
                 ushort* __restrict__ w2l)
{
    const int tid = threadIdx.x;
    if (blockIdx.x >= 512) {
        // ---- pack W1c (8192 threads) and W2 (2048 threads) into B-frag order ----
        const int gid = (blockIdx.x - 512) * 256 + tid;
        const float* srcW; ushort *dh, *dl;
        int fb, kt, col, kbase, stride, base;
        if (gid < 8192) {            // W1c: frag blocks fb = kt*16 + ntg, kt<8, ntg<16
            fb = gid >> 6; kt = fb >> 4;
            const int ntg = fb & 15, ln = gid & 63;
            col = ntg * 16 + (ln & 15); kbase = kt * 32 + (ln >> 4) * 8;
            srcW = W1 + 2 * ND * ND; stride = ND; dh = w1h; dl = w1l; base = gid * 8;
        } else {                     // W2: fb = kt*4 + ntg, kt<8, ntg<4
            const int g2 = gid - 8192;
            fb = g2 >> 6; kt = fb >> 2;
            const int ntg = fb & 3, ln = g2 & 63;
            col = ntg * 16 + (ln & 15); kbase = kt * 32 + (ln >> 4) * 8;
            srcW = W2; stride = 64; dh = w2h; dl = w2l; base = g2 * 8;
        }
        uint hv[4], lv[4];
        #pragma unroll
        for (int p = 0; p < 4; ++p) {
            const float a = srcW[(kbase + 2 * p) * stride + col];
            const float b = srcW[(kbase + 2 * p + 1) * stride + col];
            split2(a, b, hv[p], lv[p]);
        }
        *(uint4*)(dh + base) = make_uint4(hv[0], hv[1], hv[2], hv[3]);
        *(uint4*)(dl + base) = make_uint4(lv[0], lv[1], lv[2], lv[3]);
        return;
    }
    // ---- U/V: 512 blocks, 16-row x 128-col tiles (fp32 exact) ----
    const int half = blockIdx.x >> 8;
    const int rem  = blockIdx.x & 255;
    const int rb   = rem >> 1;
    const int colh = rem & 1;
    const float* src = half ? s_t1 : s_t;
    const float* W   = W1 + half * ND * ND;
    float* dst = half ? V : U;
    __shared__ float sL[16 * ND];
    const int rbase = rb * 16;
    #pragma unroll
    for (int t = 0; t < 4; ++t) {
        const int i4 = ((t << 8) + tid) << 2;
        float4 a = *(const float4*)(src + rbase * ND + i4);
        a.x = clip50(a.x); a.y = clip50(a.y); a.z = clip50(a.z); a.w = clip50(a.w);
        *(float4*)(sL + i4) = a;
    }
    __syncthreads();
    const int wv   = tid >> 6;
    const int lane = tid & 63;
    const int tj1  = lane >> 5;
    const int tc   = lane & 31;
    const int r0   = wv * 4 + tj1 * 2;
    const int c0   = colh * 128 + tc * 4;
    float acc[2][4] = {};
    for (int k4 = 0; k4 < ND; k4 += 4) {
        float4 sv[2];
        #pragma unroll
        for (int r = 0; r < 2; ++r) sv[r] = *(const float4*)(sL + (r0 + r) * ND + k4);
        #pragma unroll
        for (int kk = 0; kk < 4; ++kk) {
            const float4 wvv = *(const float4*)(W + (k4 + kk) * ND + c0);
            #pragma unroll
            for (int r = 0; r < 2; ++r) {
                const float s = (&sv[r].x)[kk];
                acc[r][0] = fmaf(s, wvv.x, acc[r][0]);
                acc[r][1] = fmaf(s, wvv.y, acc[r][1]);
                acc[r][2] = fmaf(s, wvv.z, acc[r][2]);
                acc[r][3] = fmaf(s, wvv.w, acc[r][3]);
            }
        }
    }
    float4 bias = make_float4(0.f, 0.f, 0.f, 0.f);
    if (!half) bias = *(const float4*)(b1 + c0);
    #pragma unroll
    for (int r = 0; r < 2; ++r) {
        float4 o;
        o.x = acc[r][0] + bias.x; o.y = acc[r][1] + bias.y;
        o.z = acc[r][2] + bias.z; o.w = acc[r][3] + bias.w;
        *(float4*)(dst + (rbase + r0 + r) * ND + c0) = o;
    }
}

// ---------------- K2: per-(b,i,jh) pair-MLP via split-bf16 MFMA ----------------
// M-split: block = (bi, jh) handles 32 j-rows. LDS planes 16 KB each -> 4 blocks/CU.
// Wave w owns output cols [64w, 64w+64) in phase 2 and N-tile w in phase 3.
// 16x16x32 MFMA layouts: A: m=lane&15, k=(lane>>4)*8+j ; C/D: col=lane&15, row=(lane>>4)*4+reg.
__global__ __launch_bounds__(256, 4)
void k2_scores(const float* __restrict__ s_t, const float* __restrict__ s_t1,
               const float* __restrict__ b2, const float* __restrict__ W3,
               const float* __restrict__ b3, const float* __restrict__ alive_t,
               const float* __restrict__ alive_t1,
               const float* __restrict__ U, const float* __restrict__ V,
               const ushort* __restrict__ w1h, const ushort* __restrict__ w1l,
               const ushort* __restrict__ w2h, const ushort* __restrict__ w2l,
               float* __restrict__ laG)
{
    __shared__ ushort sAh[MH * ND];    // 16 KB
    __shared__ ushort sAl[MH * ND];    // 16 KB
    __shared__ float  red[4 * MH];     // 512 B
    const int tid = threadIdx.x;
    const int bi  = blockIdx.x >> 1;
    const int jh  = blockIdx.x & 1;
    const int b   = bi >> 6;
    const int jbase = jh * MH;
    const int lane = tid & 63;
    const int w    = tid >> 6;
    const int mlane = lane & 15;       // frag row/col within tile
    const int kg    = lane >> 4;       // k-group 0..3

    // ---- phase 1: diff = |clip(s_t[i]) - clip(s_t1[jbase+m])| -> hi/lo planes ----
    {
        const float* stb = s_t + bi * ND;
        const float* s1b = s_t1 + (size_t)b * NN * ND + (size_t)jbase * ND;
        #pragma unroll
        for (int t = 0; t < 4; ++t) {
            const int slot = (t << 8) + tid;       // 1024 slots of 8 k
            const int m  = slot >> 5;              // local row 0..31
            const int k0 = (slot & 31) << 3;
            const float4 a0 = *(const float4*)(stb + k0);
            const float4 a1 = *(const float4*)(stb + k0 + 4);
            const float4 p0 = *(const float4*)(s1b + m * ND + k0);
            const float4 p1 = *(const float4*)(s1b + m * ND + k0 + 4);
            float d[8];
            d[0] = fabsf(clip50(a0.x) - clip50(p0.x));
            d[1] = fabsf(clip50(a0.y) - clip50(p0.y));
            d[2] = fabsf(clip50(a0.z) - clip50(p0.z));
            d[3] = fabsf(clip50(a0.w) - clip50(p0.w));
            d[4] = fabsf(clip50(a1.x) - clip50(p1.x));
            d[5] = fabsf(clip50(a1.y) - clip50(p1.y));
            d[6] = fabsf(clip50(a1.z) - clip50(p1.z));
            d[7] = fabsf(clip50(a1.w) - clip50(p1.w));
            uint hv[4], lv[4];
            #pragma unroll
            for (int p = 0; p < 4; ++p) split2(d[2*p], d[2*p+1], hv[p], lv[p]);
            const int off = ASW(m, k0 * 2);
            *(uint4*)((char*)sAh + off) = make_uint4(hv[0], hv[1], hv[2], hv[3]);
            *(uint4*)((char*)sAl + off) = make_uint4(lv[0], lv[1], lv[2], lv[3]);
        }
    }
    __syncthreads();

    // ---- phase 2: C1 = diff @ W1c  (M=32, N=64 per wave, K=256) ----
    f32x4 acc[2][4];
    #pragma unroll
    for (int mt = 0; mt < 2; ++mt)
        #pragma unroll
        for (int nt = 0; nt < 4; ++nt)
            #pragma unroll
            for (int r = 0; r < 4; ++r) acc[mt][nt][r] = 0.f;
    #pragma unroll
    for (int kt = 0; kt < 8; ++kt) {
        bfrag Bh[4], Bl[4], Ah[2], Al[2];
        #pragma unroll
        for (int nt = 0; nt < 4; ++nt) {
            const int fo = (kt * 16 + (w << 2) + nt) * 512 + lane * 8;
            Bh[nt] = *(const bfrag*)(w1h + fo);
            Bl[nt] = *(const bfrag*)(w1l + fo);
        }
        const int k2b = (kt * 32 + kg * 8) * 2;
        #pragma unroll
        for (int mt = 0; mt < 2; ++mt) {
            const int m = mt * 16 + mlane;
            const int off = ASW(m, k2b);
            Ah[mt] = *(const bfrag*)((const char*)sAh + off);
            Al[mt] = *(const bfrag*)((const char*)sAl + off);
        }
        #pragma unroll
        for (int mt = 0; mt < 2; ++mt)
            #pragma unroll
            for (int nt = 0; nt < 4; ++nt) {
                acc[mt][nt] = __builtin_amdgcn_mfma_f32_16x16x32_bf16(Ah[mt], Bh[nt], acc[mt][nt], 0, 0, 0);
                acc[mt][nt] = __builtin_amdgcn_mfma_f32_16x16x32_bf16(Ah[mt], Bl[nt], acc[mt][nt], 0, 0, 0);
                acc[mt][nt] = __builtin_amdgcn_mfma_f32_16x16x32_bf16(Al[mt], Bh[nt], acc[mt][nt], 0, 0, 0);
            }
    }
    __syncthreads();   // all phase-2 A reads done before h1 overwrites planes

    // ---- epilogue: h1 = relu(C1 + U[bi,c] + V[b,jbase+j,c]) -> hi/lo planes ----
    {
        const float* Ur = U + (size_t)bi * ND;
        const float* Vb = V + (size_t)b * NN * ND + (size_t)jbase * ND;
        float Uc[4];
        #pragma unroll
        for (int nt = 0; nt < 4; ++nt) Uc[nt] = Ur[w * 64 + nt * 16 + mlane];
        #pragma unroll
        for (int mt = 0; mt < 2; ++mt) {
            #pragma unroll
            for (int r = 0; r < 4; ++r) {
                const int j = mt * 16 + (kg << 2) + r;     // local row
                const float* Vr = Vb + (size_t)j * ND;
                #pragma unroll
                for (int nt = 0; nt < 4; ++nt) {
                    const int c = w * 64 + nt * 16 + mlane;
                    float x = acc[mt][nt][r] + Uc[nt] + Vr[c];
                    x = fmaxf(x, 0.f);
                    const ushort hh = bf16_rne(x);
                    const float  fh = __builtin_bit_cast(float, (uint)hh << 16);
                    const ushort ll = bf16_rne(x - fh);
                    const int off = ASW(j, c * 2);
                    *(ushort*)((char*)sAh + off) = hh;
                    *(ushort*)((char*)sAl + off) = ll;
                }
            }
        }
    }
    __syncthreads();

    // ---- phase 3: C2 = h1 @ W2 (wave w -> N-tile w, both M-tiles) ----
    f32x4 acc2[2];
    #pragma unroll
    for (int mt = 0; mt < 2; ++mt)
        #pragma unroll
        for (int r = 0; r < 4; ++r) acc2[mt][r] = 0.f;
    #pragma unroll
    for (int kt = 0; kt < 8; ++kt) {
        const int fo = (kt * 4 + w) * 512 + lane * 8;
        const bfrag Bh = *(const bfrag*)(w2h + fo);
        const bfrag Bl = *(const bfrag*)(w2l + fo);
        const int k2b = (kt * 32 + kg * 8) * 2;
        #pragma unroll
        for (int mt = 0; mt < 2; ++mt) {
            const int m = mt * 16 + mlane;
            const int off = ASW(m, k2b);
            const bfrag Ah = *(const bfrag*)((const char*)sAh + off);
            const bfrag Al = *(const bfrag*)((const char*)sAl + off);
            acc2[mt] = __builtin_amdgcn_mfma_f32_16x16x32_bf16(Ah, Bh, acc2[mt], 0, 0, 0);
            acc2[mt] = __builtin_amdgcn_mfma_f32_16x16x32_bf16(Ah, Bl, acc2[mt], 0, 0, 0);
            acc2[mt] = __builtin_amdgcn_mfma_f32_16x16x32_bf16(Al, Bh, acc2[mt], 0, 0, 0);
        }
    }

    // ---- final: h2 = relu(C2 + b2); partial score = sum_m h2*W3 ----
    {
        const int m = w * 16 + mlane;
        const float b2v = b2[m];
        const float w3v = W3[m];
        #pragma unroll
        for (int mt = 0; mt < 2; ++mt) {
            #pragma unroll
            for (int r = 0; r < 4; ++r) {
                const int j = mt * 16 + (kg << 2) + r;     // local row
                float val = fmaxf(acc2[mt][r] + b2v, 0.f) * w3v;
                val += __shfl_xor(val, 1, 64);
                val += __shfl_xor(val, 2, 64);
                val += __shfl_xor(val, 4, 64);
                val += __shfl_xor(val, 8, 64);
                if (mlane == 0) red[w * MH + j] = val;
            }
        }
    }
    __syncthreads();
    if (tid < MH) {
        const int j = tid;                                 // local row
        const float sc = red[j] + red[MH + j] + red[2 * MH + j] + red[3 * MH + j] + b3[0];
        const float pen_i = (alive_t[bi] < 0.5f) ? PEN : 0.0f;
        const float pj = (alive_t1[b * NN + jbase + j] < 0.5f) ? PEN : 0.0f;
        const float sp = sc - pen_i - pj;
        laG[bi * NN + jbase + j] = fminf(fmaxf(sp, -PEN), PEN) / TEMP_;
    }
}

// ---------------- K3: Sinkhorn (20 iters) + argmax/matched ----------------
__global__ __launch_bounds__(256)
void k3_sinkhorn(const float* __restrict__ laG, const float* __restrict__ alive_t,
                 const float* __restrict__ alive_t1, float* __restrict__ out)
{
    __shared__ float la[NN * 65];
    const int b = blockIdx.x, tid = threadIdx.x;
    for (int idx = tid; idx < NN * NN; idx += 256)
        la[(idx >> 6) * 65 + (idx & 63)] = laG[b * NN * NN + idx];
    __syncthreads();

    const int g = tid >> 2;
    const int q = tid & 3;
    for (int it = 0; it < 20; ++it) {
        {
            float m = -INFINITY;
            #pragma unroll
            for (int t = 0; t < 16; ++t) m = fmaxf(m, la[g * 65 + q * 16 + t]);
            m = fmaxf(m, __shfl_xor(m, 1, 64));
            m = fmaxf(m, __shfl_xor(m, 2, 64));
            float s = 0.f;
            #pragma unroll
            for (int t = 0; t < 16; ++t) s += expf(la[g * 65 + q * 16 + t] - m);
            s += __shfl_xor(s, 1, 64);
            s += __shfl_xor(s, 2, 64);
            const float lse = m + logf(s);
            #pragma unroll
            for (int t = 0; t < 16; ++t) la[g * 65 + q * 16 + t] -= lse;
        }
        __syncthreads();
        {
            float m = -INFINITY;
            #pragma unroll
            for (int t = 0; t < 16; ++t) m = fmaxf(m, la[(q * 16 + t) * 65 + g]);
            m = fmaxf(m, __shfl_xor(m, 1, 64));
            m = fmaxf(m, __shfl_xor(m, 2, 64));
            float s = 0.f;
            #pragma unroll
            for (int t = 0; t < 16; ++t) s += expf(la[(q * 16 + t) * 65 + g] - m);
            s += __shfl_xor(s, 1, 64);
            s += __shfl_xor(s, 2, 64);
            const float lse = m + logf(s);
            #pragma unroll
            for (int t = 0; t < 16; ++t) la[(q * 16 + t) * 65 + g] -= lse;
        }
        __syncthreads();
    }

    float bm = -INFINITY; int bidx = 0;
    #pragma unroll
    for (int t = 0; t < 16; ++t) {
        const float v = la[g * 65 + q * 16 + t];
        if (v > bm) { bm = v; bidx = q * 16 + t; }
    }
    #pragma unroll
    for (int off = 1; off < 4; off <<= 1) {
        const float om = __shfl_xor(bm, off, 64);
        const int   oi = __shfl_xor(bidx, off, 64);
        if (om > bm || (om == bm && oi < bidx)) { bm = om; bidx = oi; }
    }
    if (q == 0) {
        const float conf = expf(bm);
        const float at  = alive_t[b * NN + g];
        const float at1 = alive_t1[b * NN + bidx];
        const float matched = (at > 0.5f && at1 > 0.5f && conf > 0.3f) ? 1.0f : 0.0f;
        out[b * NN + g] = (float)bidx;
        out[NB * NN + b * NN + g] = matched;
    }
}

extern "C" void kernel_launch(void* const* d_in, const int* in_sizes, int n_in,
                              void* d_out, int out_size, void* d_ws, size_t ws_size,
                              hipStream_t stream)
{
    (void)in_sizes; (void)n_in; (void)out_size; (void)ws_size;
    const float* s_t      = (const float*)d_in[0];
    const float* s_t1     = (const float*)d_in[1];
    const float* alive_t  = (const float*)d_in[2];
    const float* alive_t1 = (const float*)d_in[3];
    const float* W1 = (const float*)d_in[4];
    const float* b1 = (const float*)d_in[5];
    const float* W2 = (const float*)d_in[6];
    const float* b2 = (const float*)d_in[7];
    const float* W3 = (const float*)d_in[8];
    const float* b3 = (const float*)d_in[9];

    char* ws = (char*)d_ws;
    float*  U   = (float*)(ws);                         // 2 MB
    float*  V   = (float*)(ws + 2097152);               // 2 MB
    float*  laG = (float*)(ws + 4194304);               // 512 KB
    ushort* w1h = (ushort*)(ws + 4718592);              // 128 KB
    ushort* w1l = (ushort*)(ws + 4849664);              // 128 KB
    ushort* w2h = (ushort*)(ws + 4980736);              // 32 KB
    ushort* w2l = (ushort*)(ws + 5013504);              // 32 KB
    float* out = (float*)d_out;

    hipLaunchKernelGGL(k01_uv_pack, dim3(552), dim3(256), 0, stream,
                       s_t, s_t1, W1, b1, W2, U, V, w1h, w1l, w2h, w2l);
    hipLaunchKernelGGL(k2_scores, dim3(NB * NN * 2), dim3(256), 0, stream,
                       s_t, s_t1, b2, W3, b3, alive_t, alive_t1, U, V,
                       w1h, w1l, w2h, w2l, laG);
    hipLaunchKernelGGL(k3_sinkhorn, dim3(NB), dim3(256), 0, stream,
                       laG, alive_t, alive_t1, out);
}

// Round 6
// 201.309 us; speedup vs baseline: 2.1572x; 1.0317x over previous
//
#include <hip/hip_runtime.h>

#define NB 32
#define NN 64
#define ND 256
#define MH 32   // rows (j) per k2 block after M-split
constexpr float PEN = 10000.0f;
constexpr float TEMP_ = 0.05f;

typedef __bf16 bfrag __attribute__((ext_vector_type(8)));   // 8 bf16 = 4 VGPR (MFMA A/B)
typedef float  f32x4 __attribute__((ext_vector_type(4)));   // MFMA C/D

__device__ __forceinline__ float clip50(float x) { return fminf(fmaxf(x, -50.0f), 50.0f); }
__device__ __forceinline__ ushort bfbits(__bf16 h) { return __builtin_bit_cast(ushort, h); }
__device__ __forceinline__ float bf2f(__bf16 h) {
    return __builtin_bit_cast(float, (uint)bfbits(h) << 16);
}
// round-to-nearest-even f32 -> bf16 bit pattern (pack kernel only)
__device__ __forceinline__ ushort bf16_rne(float x) {
    uint u = __builtin_bit_cast(uint, x);
    return (ushort)((u + 0x7fffu + ((u >> 16) & 1u)) >> 16);
}
__device__ __forceinline__ void split2(float a, float b, uint& h, uint& l) {
    const ushort ha = bf16_rne(a), hb = bf16_rne(b);
    const float fa = __builtin_bit_cast(float, (uint)ha << 16);
    const float fb = __builtin_bit_cast(float, (uint)hb << 16);
    const ushort la = bf16_rne(a - fa), lb = bf16_rne(b - fb);
    h = (uint)ha | ((uint)hb << 16);
    l = (uint)la | ((uint)lb << 16);
}
// LDS A/B-plane swizzle: element (row m, col k) bf16 at byte m*512 + (2k ^ ((m&7)<<4))
#define ASW(m, k2) ((m) * 512 + ((k2) ^ (((m) & 7) << 4)))

// ---------------- K01: U/V GEMMs (blocks 0..511) + W-pack (blocks 512..551) ----
__global__ __launch_bounds__(256)
void k01_uv_pack(const float* __restrict__ s_t, const float* __restrict__ s_t1,
                 const float* __restrict__ W1, const float* __restrict__ b1,
                 const float* __restrict__ W2, float* __restrict__ U,
                 float* __restrict__ V, ushort* __restrict__ w1h,
                 ushort* __restrict__ w1l, ushort* __restrict__ w2h,
                 ushort* __restrict__ w2l)
{
    const int tid = threadIdx.x;
    if (blockIdx.x >= 512) {
        // ---- pack W1c (8192 threads) and W2 (2048 threads) into frag order ----
        // frag lane-map (A or B operand, identical on gfx950):
        //   elem (lane, p): dim = tile*16 + (lane&15), k = kt*32 + (lane>>4)*8 + p
        const int gid = (blockIdx.x - 512) * 256 + tid;
        const float* srcW; ushort *dh, *dl;
        int fb, kt, col, kbase, stride, base;
        if (gid < 8192) {            // W1c: fb = kt*16 + ctile, kt<8, ctile<16
            fb = gid >> 6; kt = fb >> 4;
            const int ntg = fb & 15, ln = gid & 63;
            col = ntg * 16 + (ln & 15); kbase = kt * 32 + (ln >> 4) * 8;
            srcW = W1 + 2 * ND * ND; stride = ND; dh = w1h; dl = w1l; base = gid * 8;
        } else {                     // W2: fb = kt*4 + ntile, kt<8, ntile<4
            const int g2 = gid - 8192;
            fb = g2 >> 6; kt = fb >> 2;
            const int ntg = fb & 3, ln = g2 & 63;
            col = ntg * 16 + (ln & 15); kbase = kt * 32 + (ln >> 4) * 8;
            srcW = W2; stride = 64; dh = w2h; dl = w2l; base = g2 * 8;
        }
        uint hv[4], lv[4];
        #pragma unroll
        for (int p = 0; p < 4; ++p) {
            const float a = srcW[(kbase + 2 * p) * stride + col];
            const float b = srcW[(kbase + 2 * p + 1) * stride + col];
            split2(a, b, hv[p], lv[p]);
        }
        *(uint4*)(dh + base) = make_uint4(hv[0], hv[1], hv[2], hv[3]);
        *(uint4*)(dl + base) = make_uint4(lv[0], lv[1], lv[2], lv[3]);
        return;
    }
    // ---- U/V: 512 blocks, 16-row x 128-col tiles (fp32 exact) ----
    const int half = blockIdx.x >> 8;
    const int rem  = blockIdx.x & 255;
    const int rb   = rem >> 1;
    const int colh = rem & 1;
    const float* src = half ? s_t1 : s_t;
    const float* W   = W1 + half * ND * ND;
    float* dst = half ? V : U;
    __shared__ float sL[16 * ND];
    const int rbase = rb * 16;
    #pragma unroll
    for (int t = 0; t < 4; ++t) {
        const int i4 = ((t << 8) + tid) << 2;
        float4 a = *(const float4*)(src + rbase * ND + i4);
        a.x = clip50(a.x); a.y = clip50(a.y); a.z = clip50(a.z); a.w = clip50(a.w);
        *(float4*)(sL + i4) = a;
    }
    __syncthreads();
    const int wv   = tid >> 6;
    const int lane = tid & 63;
    const int tj1  = lane >> 5;
    const int tc   = lane & 31;
    const int r0   = wv * 4 + tj1 * 2;
    const int c0   = colh * 128 + tc * 4;
    float acc[2][4] = {};
    for (int k4 = 0; k4 < ND; k4 += 4) {
        float4 sv[2];
        #pragma unroll
        for (int r = 0; r < 2; ++r) sv[r] = *(const float4*)(sL + (r0 + r) * ND + k4);
        #pragma unroll
        for (int kk = 0; kk < 4; ++kk) {
            const float4 wvv = *(const float4*)(W + (k4 + kk) * ND + c0);
            #pragma unroll
            for (int r = 0; r < 2; ++r) {
                const float s = (&sv[r].x)[kk];
                acc[r][0] = fmaf(s, wvv.x, acc[r][0]);
                acc[r][1] = fmaf(s, wvv.y, acc[r][1]);
                acc[r][2] = fmaf(s, wvv.z, acc[r][2]);
                acc[r][3] = fmaf(s, wvv.w, acc[r][3]);
            }
        }
    }
    float4 bias = make_float4(0.f, 0.f, 0.f, 0.f);
    if (!half) bias = *(const float4*)(b1 + c0);
    #pragma unroll
    for (int r = 0; r < 2; ++r) {
        float4 o;
        o.x = acc[r][0] + bias.x; o.y = acc[r][1] + bias.y;
        o.z = acc[r][2] + bias.z; o.w = acc[r][3] + bias.w;
        *(float4*)(dst + (rbase + r0 + r) * ND + c0) = o;
    }
}

// ---------------- K2: per-(b,i,jh) pair-MLP via split-bf16 MFMA ----------------
// Phase 2 is operand-SWAPPED: A = W1c^T (M-dim = c), B = diff (N-dim = j).
// C/D then holds D[c][j] with c = ct*16 + kg*4 + r (4 CONSECUTIVE c per lane) and
// j = jt*16 + mlane -> float4 U/V epilogue loads and b64 h1 stores.
// Phase 3 unchanged: A = h1 (M=j), B = W2 (N=m), C2[j][m].
__global__ __launch_bounds__(256, 4)
void k2_scores(const float* __restrict__ s_t, const float* __restrict__ s_t1,
               const float* __restrict__ b2, const float* __restrict__ W3,
               const float* __restrict__ b3, const float* __restrict__ alive_t,
               const float* __restrict__ alive_t1,
               const float* __restrict__ U, const float* __restrict__ V,
               const ushort* __restrict__ w1h, const ushort* __restrict__ w1l,
               const ushort* __restrict__ w2h, const ushort* __restrict__ w2l,
               float* __restrict__ laG)
{
    __shared__ ushort sAh[MH * ND];    // 16 KB
    __shared__ ushort sAl[MH * ND];    // 16 KB
    __shared__ float  red[4 * MH];     // 512 B
    const int tid = threadIdx.x;
    const int bi  = blockIdx.x >> 1;
    const int jh  = blockIdx.x & 1;
    const int b   = bi >> 6;
    const int jbase = jh * MH;
    const int lane = tid & 63;
    const int w    = tid >> 6;
    const int mlane = lane & 15;
    const int kg    = lane >> 4;

    // ---- phase 1: diff = |clip(s_t[i]) - clip(s_t1[jbase+m])| -> hi/lo planes ----
    {
        const float* stb = s_t + bi * ND;
        const float* s1b = s_t1 + (size_t)b * NN * ND + (size_t)jbase * ND;
        #pragma unroll
        for (int t = 0; t < 4; ++t) {
            const int slot = (t << 8) + tid;       // 1024 slots of 8 k
            const int m  = slot >> 5;              // local row 0..31
            const int k0 = (slot & 31) << 3;
            const float4 a0 = *(const float4*)(stb + k0);
            const float4 a1 = *(const float4*)(stb + k0 + 4);
            const float4 p0 = *(const float4*)(s1b + m * ND + k0);
            const float4 p1 = *(const float4*)(s1b + m * ND + k0 + 4);
            float d[8];
            d[0] = fabsf(clip50(a0.x) - clip50(p0.x));
            d[1] = fabsf(clip50(a0.y) - clip50(p0.y));
            d[2] = fabsf(clip50(a0.z) - clip50(p0.z));
            d[3] = fabsf(clip50(a0.w) - clip50(p0.w));
            d[4] = fabsf(clip50(a1.x) - clip50(p1.x));
            d[5] = fabsf(clip50(a1.y) - clip50(p1.y));
            d[6] = fabsf(clip50(a1.z) - clip50(p1.z));
            d[7] = fabsf(clip50(a1.w) - clip50(p1.w));
            uint hv[4], lv[4];
            #pragma unroll
            for (int p = 0; p < 4; ++p) {
                const __bf16 ha = (__bf16)d[2*p], hb = (__bf16)d[2*p+1];
                const __bf16 la_ = (__bf16)(d[2*p]   - bf2f(ha));
                const __bf16 lb_ = (__bf16)(d[2*p+1] - bf2f(hb));
                hv[p] = (uint)bfbits(ha) | ((uint)bfbits(hb) << 16);
                lv[p] = (uint)bfbits(la_) | ((uint)bfbits(lb_) << 16);
            }
            const int off = ASW(m, k0 * 2);
            *(uint4*)((char*)sAh + off) = make_uint4(hv[0], hv[1], hv[2], hv[3]);
            *(uint4*)((char*)sAl + off) = make_uint4(lv[0], lv[1], lv[2], lv[3]);
        }
    }
    __syncthreads();

    // ---- phase 2 (swapped): D[c][j] = sum_k W1c[k][c] * diff[j][k] ----
    f32x4 acc[4][2];   // [ct][jt]
    #pragma unroll
    for (int ct = 0; ct < 4; ++ct)
        #pragma unroll
        for (int jt = 0; jt < 2; ++jt)
            #pragma unroll
            for (int r = 0; r < 4; ++r) acc[ct][jt][r] = 0.f;
    #pragma unroll
    for (int kt = 0; kt < 8; ++kt) {
        bfrag Ah[4], Al[4], Bh[2], Bl[2];
        #pragma unroll
        for (int ct = 0; ct < 4; ++ct) {
            const int fo = (kt * 16 + (w << 2) + ct) * 512 + lane * 8;
            Ah[ct] = *(const bfrag*)(w1h + fo);
            Al[ct] = *(const bfrag*)(w1l + fo);
        }
        const int k2b = (kt * 32 + kg * 8) * 2;
        #pragma unroll
        for (int jt = 0; jt < 2; ++jt) {
            const int off = ASW(jt * 16 + mlane, k2b);
            Bh[jt] = *(const bfrag*)((const char*)sAh + off);
            Bl[jt] = *(const bfrag*)((const char*)sAl + off);
        }
        #pragma unroll
        for (int ct = 0; ct < 4; ++ct)
            #pragma unroll
            for (int jt = 0; jt < 2; ++jt) {
                acc[ct][jt] = __builtin_amdgcn_mfma_f32_16x16x32_bf16(Ah[ct], Bh[jt], acc[ct][jt], 0, 0, 0);
                acc[ct][jt] = __builtin_amdgcn_mfma_f32_16x16x32_bf16(Ah[ct], Bl[jt], acc[ct][jt], 0, 0, 0);
                acc[ct][jt] = __builtin_amdgcn_mfma_f32_16x16x32_bf16(Al[ct], Bh[jt], acc[ct][jt], 0, 0, 0);
            }
    }
    __syncthreads();   // all phase-2 B reads done before h1 overwrites planes

    // ---- epilogue: h1 = relu(D + U[bi,c] + V[b,jbase+j,c]) -> hi/lo planes ----
    // Lane holds 4 consecutive c (r=0..3) for fixed j: float4 U/V, b64 LDS stores.
    {
        const float* Ur = U + (size_t)bi * ND;
        const float* Vb = V + (size_t)b * NN * ND + (size_t)jbase * ND;
        #pragma unroll
        for (int ct = 0; ct < 4; ++ct) {
            const int c0 = (w << 6) + ct * 16 + (kg << 2);
            const float4 uq = *(const float4*)(Ur + c0);
            #pragma unroll
            for (int jt = 0; jt < 2; ++jt) {
                const int j = jt * 16 + mlane;         // local row
                const float4 vq = *(const float4*)(Vb + (size_t)j * ND + c0);
                float x[4];
                x[0] = fmaxf(acc[ct][jt][0] + uq.x + vq.x, 0.f);
                x[1] = fmaxf(acc[ct][jt][1] + uq.y + vq.y, 0.f);
                x[2] = fmaxf(acc[ct][jt][2] + uq.z + vq.z, 0.f);
                x[3] = fmaxf(acc[ct][jt][3] + uq.w + vq.w, 0.f);
                const __bf16 h0 = (__bf16)x[0], h1v = (__bf16)x[1];
                const __bf16 h2 = (__bf16)x[2], h3 = (__bf16)x[3];
                const __bf16 l0 = (__bf16)(x[0] - bf2f(h0)), l1 = (__bf16)(x[1] - bf2f(h1v));
                const __bf16 l2 = (__bf16)(x[2] - bf2f(h2)), l3 = (__bf16)(x[3] - bf2f(h3));
                uint2 hq, lq;
                hq.x = (uint)bfbits(h0) | ((uint)bfbits(h1v) << 16);
                hq.y = (uint)bfbits(h2) | ((uint)bfbits(h3) << 16);
                lq.x = (uint)bfbits(l0) | ((uint)bfbits(l1) << 16);
                lq.y = (uint)bfbits(l2) | ((uint)bfbits(l3) << 16);
                const int off = ASW(j, c0 * 2);
                *(uint2*)((char*)sAh + off) = hq;
                *(uint2*)((char*)sAl + off) = lq;
            }
        }
    }
    __syncthreads();

    // ---- phase 3: C2 = h1 @ W2 (wave w -> N-tile w, both M-tiles) ----
    f32x4 acc2[2];
    #pragma unroll
    for (int mt = 0; mt < 2; ++mt)
        #pragma unroll
        for (int r = 0; r < 4; ++r) acc2[mt][r] = 0.f;
    #pragma unroll
    for (int kt = 0; kt < 8; ++kt) {
        const int fo = (kt * 4 + w) * 512 + lane * 8;
        const bfrag Bh = *(const bfrag*)(w2h + fo);
        const bfrag Bl = *(const bfrag*)(w2l + fo);
        const int k2b = (kt * 32 + kg * 8) * 2;
        #pragma unroll
        for (int mt = 0; mt < 2; ++mt) {
            const int m = mt * 16 + mlane;
            const int off = ASW(m, k2b);
            const bfrag Ah = *(const bfrag*)((const char*)sAh + off);
            const bfrag Al = *(const bfrag*)((const char*)sAl + off);
            acc2[mt] = __builtin_amdgcn_mfma_f32_16x16x32_bf16(Ah, Bh, acc2[mt], 0, 0, 0);
            acc2[mt] = __builtin_amdgcn_mfma_f32_16x16x32_bf16(Ah, Bl, acc2[mt], 0, 0, 0);
            acc2[mt] = __builtin_amdgcn_mfma_f32_16x16x32_bf16(Al, Bh, acc2[mt], 0, 0, 0);
        }
    }

    // ---- final: h2 = relu(C2 + b2); partial score = sum_m h2*W3 ----
    {
        const int m = w * 16 + mlane;
        const float b2v = b2[m];
        const float w3v = W3[m];
        #pragma unroll
        for (int mt = 0; mt < 2; ++mt) {
            #pragma unroll
            for (int r = 0; r < 4; ++r) {
                const int j = mt * 16 + (kg << 2) + r;     // local row
                float val = fmaxf(acc2[mt][r] + b2v, 0.f) * w3v;
                val += __shfl_xor(val, 1, 64);
                val += __shfl_xor(val, 2, 64);
                val += __shfl_xor(val, 4, 64);
                val += __shfl_xor(val, 8, 64);
                if (mlane == 0) red[w * MH + j] = val;
            }
        }
    }
    __syncthreads();
    if (tid < MH) {
        const int j = tid;                                 // local row
        const float sc = red[j] + red[MH + j] + red[2 * MH + j] + red[3 * MH + j] + b3[0];
        const float pen_i = (alive_t[bi] < 0.5f) ? PEN : 0.0f;
        const float pj = (alive_t1[b * NN + jbase + j] < 0.5f) ? PEN : 0.0f;
        const float sp = sc - pen_i - pj;
        laG[bi * NN + jbase + j] = fminf(fmaxf(sp, -PEN), PEN) / TEMP_;
    }
}

// ---------------- K3: Sinkhorn (20 iters) + argmax/matched, 512 threads ----------------
__global__ __launch_bounds__(512)
void k3_sinkhorn(const float* __restrict__ laG, const float* __restrict__ alive_t,
                 const float* __restrict__ alive_t1, float* __restrict__ out)
{
    __shared__ float la[NN * 65];          // pad 65: both passes conflict-free
    const int b = blockIdx.x, tid = threadIdx.x;
    for (int idx = tid; idx < NN * NN; idx += 512)
        la[(idx >> 6) * 65 + (idx & 63)] = laG[b * NN * NN + idx];
    __syncthreads();

    const int g = tid >> 3;                // row/col index 0..63
    const int q = tid & 7;                 // eighth (8 elements each)
    for (int it = 0; it < 20; ++it) {
        {   // axis=2: normalize rows (over c)
            float m = -INFINITY;
            #pragma unroll
            for (int t = 0; t < 8; ++t) m = fmaxf(m, la[g * 65 + q * 8 + t]);
            m = fmaxf(m, __shfl_xor(m, 1, 64));
            m = fmaxf(m, __shfl_xor(m, 2, 64));
            m = fmaxf(m, __shfl_xor(m, 4, 64));
            float s = 0.f;
            #pragma unroll
            for (int t = 0; t < 8; ++t) s += expf(la[g * 65 + q * 8 + t] - m);
            s += __shfl_xor(s, 1, 64);
            s += __shfl_xor(s, 2, 64);
            s += __shfl_xor(s, 4, 64);
            const float lse = m + logf(s);
            #pragma unroll
            for (int t = 0; t < 8; ++t) la[g * 65 + q * 8 + t] -= lse;
        }
        __syncthreads();
        {   // axis=1: normalize cols (over r)
            float m = -INFINITY;
            #pragma unroll
            for (int t = 0; t < 8; ++t) m = fmaxf(m, la[(q * 8 + t) * 65 + g]);
            m = fmaxf(m, __shfl_xor(m, 1, 64));
            m = fmaxf(m, __shfl_xor(m, 2, 64));
            m = fmaxf(m, __shfl_xor(m, 4, 64));
            float s = 0.f;
            #pragma unroll
            for (int t = 0; t < 8; ++t) s += expf(la[(q * 8 + t) * 65 + g] - m);
            s += __shfl_xor(s, 1, 64);
            s += __shfl_xor(s, 2, 64);
            s += __shfl_xor(s, 4, 64);
            const float lse = m + logf(s);
            #pragma unroll
            for (int t = 0; t < 8; ++t) la[(q * 8 + t) * 65 + g] -= lse;
        }
        __syncthreads();
    }

    // argmax over axis 2 with first-index tie-break
    float bm = -INFINITY; int bidx = 0;
    #pragma unroll
    for (int t = 0; t < 8; ++t) {
        const float v = la[g * 65 + q * 8 + t];
        if (v > bm) { bm = v; bidx = q * 8 + t; }
    }
    #pragma unroll
    for (int off = 1; off < 8; off <<= 1) {
        const float om = __shfl_xor(bm, off, 64);
        const int   oi = __shfl_xor(bidx, off, 64);
        if (om > bm || (om == bm && oi < bidx)) { bm = om; bidx = oi; }
    }
    if (q == 0) {
        const float conf = expf(bm);
        const float at  = alive_t[b * NN + g];
        const float at1 = alive_t1[b * NN + bidx];
        const float matched = (at > 0.5f && at1 > 0.5f && conf > 0.3f) ? 1.0f : 0.0f;
        out[b * NN + g] = (float)bidx;                 // perm (written as float)
        out[NB * NN + b * NN + g] = matched;           // matched
    }
}

extern "C" void kernel_launch(void* const* d_in, const int* in_sizes, int n_in,
                              void* d_out, int out_size, void* d_ws, size_t ws_size,
                              hipStream_t stream)
{
    (void)in_sizes; (void)n_in; (void)out_size; (void)ws_size;
    const float* s_t      = (const float*)d_in[0];
    const float* s_t1     = (const float*)d_in[1];
    const float* alive_t  = (const float*)d_in[2];
    const float* alive_t1 = (const float*)d_in[3];
    const float* W1 = (const float*)d_in[4];
    const float* b1 = (const float*)d_in[5];
    const float* W2 = (const float*)d_in[6];
    const float* b2 = (const float*)d_in[7];
    const float* W3 = (const float*)d_in[8];
    const float* b3 = (const float*)d_in[9];

    char* ws = (char*)d_ws;
    float*  U   = (float*)(ws);                         // 2 MB
    float*  V   = (float*)(ws + 2097152);               // 2 MB
    float*  laG = (float*)(ws + 4194304);               // 512 KB
    ushort* w1h = (ushort*)(ws + 4718592);              // 128 KB
    ushort* w1l = (ushort*)(ws + 4849664);              // 128 KB
    ushort* w2h = (ushort*)(ws + 4980736);              // 32 KB
    ushort* w2l = (ushort*)(ws + 5013504);              // 32 KB
    float* out = (float*)d_out;

    hipLaunchKernelGGL(k01_uv_pack, dim3(552), dim3(256), 0, stream,
                       s_t, s_t1, W1, b1, W2, U, V, w1h, w1l, w2h, w2l);
    hipLaunchKernelGGL(k2_scores, dim3(NB * NN * 2), dim3(256), 0, stream,
                       s_t, s_t1, b2, W3, b3, alive_t, alive_t1, U, V,
                       w1h, w1l, w2h, w2l, laG);
    hipLaunchKernelGGL(k3_sinkhorn, dim3(NB), dim3(512), 0, stream,
                       laG, alive_t, alive_t1, out);
}